// Round 12
// baseline (2547.663 us; speedup 1.0000x reference)
//
#include <hip/hip_runtime.h>
#include <hip/hip_fp16.h>

#define B_  256
#define T_  96
#define IN_ 512
#define H_  1024
#define K1  1536          // H + IN
#define NT  (B_*T_)       // 24576

// recur_k: 4 chip-groups x 64 blocks; group owns 64 batch rows; block owns 16
// cols of W1/W2/W3 (LDS, k-major). NEW: barriers are PER-WAVE (16 independent
// pipelines of 64 waves; wave w of group g owns rows [g*64+w*16, +16)).
#define W12_OFF 0          // 98304 B
#define W3_OFF  98304      // 49152 B -> total 147456 B
typedef _Float16 f16x8 __attribute__((ext_vector_type(8)));
typedef float    f32x4 __attribute__((ext_vector_type(4)));
typedef float    f32x2 __attribute__((ext_vector_type(2)));

__device__ __forceinline__ float sigmoidf_(float z) { return 1.f/(1.f+__expf(-z)); }
__device__ __forceinline__ float tanhf_(float z)    { return 1.f - 2.f/(__expf(2.f*z)+1.f); }

// coherent (cross-XCD) access: bypass L1 + per-XCD L2
__device__ __forceinline__ uint2 ld_coh_b64(const void* p){
    uint2 r; asm volatile("global_load_dwordx2 %0, %1, off sc0 sc1" : "=&v"(r) : "v"(p)); return r;
}
__device__ __forceinline__ uint4 ld_b128(const void* p){
    uint4 r; asm volatile("global_load_dwordx4 %0, %1, off" : "=&v"(r) : "v"(p)); return r;
}
__device__ __forceinline__ unsigned ld_u16(const void* p){
    unsigned r; asm volatile("global_load_ushort %0, %1, off" : "=&v"(r) : "v"(p)); return r;
}
__device__ __forceinline__ void st_coh_u8(void* p, unsigned v){
    asm volatile("global_store_byte %0, %1, off sc0 sc1" :: "v"(p), "v"(v) : "memory");
}
#define WAITV(n) do { asm volatile("s_waitcnt vmcnt(" #n ")" ::: "memory"); \
                      __builtin_amdgcn_sched_barrier(0); } while(0)
__device__ __forceinline__ void waitv0_(){ asm volatile("s_waitcnt vmcnt(0)" ::: "memory"); }

// fp8 e4m3 helpers (OCP on gfx950)
__device__ __forceinline__ unsigned to_fp8(float x){
    return (unsigned)__builtin_amdgcn_cvt_pk_fp8_f32(x, x, 0, false) & 0xFFu;
}
__device__ __forceinline__ f16x8 expand_fp8(uint2 v){
    f32x2 p0 = __builtin_amdgcn_cvt_pk_f32_fp8(v.x, false);
    f32x2 p1 = __builtin_amdgcn_cvt_pk_f32_fp8(v.x, true);
    f32x2 p2 = __builtin_amdgcn_cvt_pk_f32_fp8(v.y, false);
    f32x2 p3 = __builtin_amdgcn_cvt_pk_f32_fp8(v.y, true);
    f16x8 o;
    o[0]=(_Float16)p0[0]; o[1]=(_Float16)p0[1];
    o[2]=(_Float16)p1[0]; o[3]=(_Float16)p1[1];
    o[4]=(_Float16)p2[0]; o[5]=(_Float16)p2[1];
    o[6]=(_Float16)p3[0]; o[7]=(_Float16)p3[1];
    return o;
}

// ---------------- prep: fp32 -> fp16 ----------------
__global__ void cvt_f32_f16_k(const float* __restrict__ src, _Float16* __restrict__ dst, int n8) {
    int i = blockIdx.x*blockDim.x + threadIdx.x;
    if (i >= n8) return;
    const float4* s = (const float4*)src;
    float4 a = s[2*(size_t)i], b = s[2*(size_t)i+1];
    f16x8 o;
    o[0]=(_Float16)a.x; o[1]=(_Float16)a.y; o[2]=(_Float16)a.z; o[3]=(_Float16)a.w;
    o[4]=(_Float16)b.x; o[5]=(_Float16)b.y; o[6]=(_Float16)b.z; o[7]=(_Float16)b.w;
    *(f16x8*)(dst + 8*(size_t)i) = o;
}

// ---------------- belta = exp(-relu(td @ Wb^T + bb)) ----------------
__global__ void __launch_bounds__(256) belta_gemm_k(const _Float16* __restrict__ td,
                                                    const _Float16* __restrict__ Wbh,
                                                    const float* __restrict__ bb,
                                                    _Float16* __restrict__ belta) {
    __shared__ _Float16 As[64][136];
    __shared__ _Float16 Bs[128][136];
    const int bid = blockIdx.x;
    const int mt = bid >> 3, nt = bid & 7;
    const int bt0 = mt*64, h0 = nt*128;
    const int tid = threadIdx.x;
    const int w = tid >> 6, l = tid & 63;
    const int wm = (w>>1)*32, wn = (w&1)*64;
    f32x4 acc[2][4] = {};
    for (int kc = 0; kc < 4; ++kc) {
        const int kbase = kc*128;
        #pragma unroll
        for (int p = 0; p < 4; ++p) {
            int unit = tid + 256*p; int r = unit>>4, cu = unit&15;
            *(uint4*)&As[r][cu*8] = *(const uint4*)(td + (size_t)(bt0+r)*IN_ + kbase + cu*8);
        }
        #pragma unroll
        for (int p = 0; p < 8; ++p) {
            int unit = tid + 256*p; int r = unit>>4, cu = unit&15;
            *(uint4*)&Bs[r][cu*8] = *(const uint4*)(Wbh + (size_t)(h0+r)*IN_ + kbase + cu*8);
        }
        __syncthreads();
        #pragma unroll
        for (int ks = 0; ks < 4; ++ks) {
            const int kk = ks*32 + (l>>4)*8;
            f16x8 a0 = *(const f16x8*)&As[wm +      (l&15)][kk];
            f16x8 a1 = *(const f16x8*)&As[wm + 16 + (l&15)][kk];
            #pragma unroll
            for (int ni = 0; ni < 4; ++ni) {
                f16x8 b = *(const f16x8*)&Bs[wn + ni*16 + (l&15)][kk];
                acc[0][ni] = __builtin_amdgcn_mfma_f32_16x16x32_f16(a0, b, acc[0][ni], 0,0,0);
                acc[1][ni] = __builtin_amdgcn_mfma_f32_16x16x32_f16(a1, b, acc[1][ni], 0,0,0);
            }
        }
        __syncthreads();
    }
    #pragma unroll
    for (int mi = 0; mi < 2; ++mi)
    #pragma unroll
    for (int ni = 0; ni < 4; ++ni)
    #pragma unroll
    for (int r = 0; r < 4; ++r) {
        int m_l = wm + mi*16 + (l>>4)*4 + r;
        int n_l = wn + ni*16 + (l&15);
        int bt = bt0 + m_l, h = h0 + n_l;
        float z = acc[mi][ni][r] + bb[h];
        belta[(size_t)bt*H_ + h] = (_Float16)__expf(-fmaxf(z, 0.f));
    }
}

// ---------------- PER-WAVE barrier (64 waves of one wave-group) ----------------
// No __syncthreads: each wave syncs only with the same-index wave of the other
// 63 blocks in its chip-group. While this wave polls, the CU's other 3 waves
// (independent pipelines) keep computing.
__device__ __forceinline__ void wave_barrier(int* flags, int wgbase, int j, int l, int it) {
    waitv0_();                 // drain this wave's coherent stores
    if (l == 0)
        __hip_atomic_store(&flags[wgbase + j], it, __ATOMIC_RELAXED, __HIP_MEMORY_SCOPE_AGENT);
    for (;;) {
        int v = __hip_atomic_load(&flags[wgbase + l], __ATOMIC_RELAXED, __HIP_MEMORY_SCOPE_AGENT);
        if (__all(v >= it)) break;
        __builtin_amdgcn_s_sleep(2);
    }
}

// ---------------- recurrent scan: LDS f16 weights + fp8 exchange + wave sync ----------------
__global__ void __launch_bounds__(256, 1) recur_k(
    const _Float16* __restrict__ xh,     // (B,T,IN) fp16, plain cached
    const _Float16* __restrict__ belh,   // (B,T,H) fp16, plain cached
    const float* __restrict__ W1, const float* __restrict__ W2, const float* __restrict__ W3,
    const float* __restrict__ b1, const float* __restrict__ b2, const float* __restrict__ b3,
    const float* __restrict__ Wo,
    unsigned char* __restrict__ ssh,     // (256,1024) fp8 scaled state — coherent exchange
    unsigned char* __restrict__ rsh,     // (256,1024) fp8 r*state — coherent exchange
    int* flags, float* __restrict__ outacc)
{
    __shared__ __align__(16) char smem[147456];
    const int bid = blockIdx.x, tid = threadIdx.x;
    const int g = bid >> 6, j = bid & 63;
    const int grow0 = g*64;
    const int w = tid >> 6;              // wave = row-slice index (rows w*16..w*16+15)
    const int l = tid & 63;
    const int lh = l >> 4;               // k-slot
    const int ll = l & 15;               // A-row / B-row within fragment
    const int wgbase = (g*4 + w)*64;     // this wave's flag slice

    // ---- prologue: weight slices -> LDS, K-MAJOR f16 (f32->f16) ----
    for (int u = tid; u < 32*192; u += 256) {        // W12: 32 rows x 192 k8-slots
        int row = u / 192, slot = u - row*192;
        const float* src = (row < 16) ? (W1 + ((size_t)(16*j + row))*K1 + slot*8)
                                      : (W2 + ((size_t)(16*j + row-16))*K1 + slot*8);
        float4 f0 = *(const float4*)src, f1 = *(const float4*)(src+4);
        f16x8 h;
        h[0]=(_Float16)f0.x; h[1]=(_Float16)f0.y; h[2]=(_Float16)f0.z; h[3]=(_Float16)f0.w;
        h[4]=(_Float16)f1.x; h[5]=(_Float16)f1.y; h[6]=(_Float16)f1.z; h[7]=(_Float16)f1.w;
        *(f16x8*)(smem + W12_OFF + (slot*32 + row)*16) = h;
    }
    for (int u = tid; u < 16*192; u += 256) {        // W3: 16 rows x 192 k8-slots
        int row = u / 192, slot = u - row*192;
        const float* src = W3 + ((size_t)(16*j + row))*K1 + slot*8;
        float4 f0 = *(const float4*)src, f1 = *(const float4*)(src+4);
        f16x8 h;
        h[0]=(_Float16)f0.x; h[1]=(_Float16)f0.y; h[2]=(_Float16)f0.z; h[3]=(_Float16)f0.w;
        h[4]=(_Float16)f1.x; h[5]=(_Float16)f1.y; h[6]=(_Float16)f1.z; h[7]=(_Float16)f1.w;
        *(f16x8*)(smem + W3_OFF + (slot*16 + row)*16) = h;
    }
    __syncthreads();                     // weights ready; last block-wide sync

    const int colU = (j<<4) + ll;                    // owned output column
    const float b1c = b1[colU], b2c = b2[colU], b3c = b3[colU];
    const float woc = Wo[colU];
    const int wb12 = lh*512 + ll*16;                 // per-lane LDS byte offsets
    const int wb3  = lh*256 + ll*16;

    // per-lane A-load bases: row = grow0 + w*16 + ll, k-offset lh*8
    const unsigned char* srow_s = ssh + ((size_t)(grow0 + w*16 + ll) << 10) + lh*8;
    const unsigned char* srow_r = rsh + ((size_t)(grow0 + w*16 + ll) << 10) + lh*8;
    const _Float16* xrow = xh + (size_t)(grow0 + w*16 + ll) * T_ * IN_ + lh*8;
    const int crow0 = grow0 + w*16 + lh*4;           // epilogue rows (+r)

    float S_reg[4] = {0.f,0.f,0.f,0.f};
    float pout[4]  = {0.f,0.f,0.f,0.f};
    uint4 abx[4][4];                                 // x frags (f16), 64 VGPR
    uint2 abs_[8][4];                                // coherent fp8 frags, 64 VGPR
    int it = 0;

    // issue macros
    #define ISSX(SX) do { _Pragma("unroll") for (int kf=0;kf<4;++kf) \
        abx[SX][kf] = ld_b128(xrt + (SX)*128 + kf*32); } while(0)
    #define ISSS(SC) do { _Pragma("unroll") for (int kf=0;kf<4;++kf) \
        abs_[SC][kf] = ld_coh_b64(srow_s + (SC)*128 + kf*32); } while(0)
    #define ISSR(SC) do { _Pragma("unroll") for (int kf=0;kf<4;++kf) \
        abs_[SC][kf] = ld_coh_b64(srow_r + (SC)*128 + kf*32); } while(0)
    // consume: S = absolute weight k-section (0..11)
    #define MF1X(S, SX) do { \
        _Pragma("unroll") for (int kf = 0; kf < 4; ++kf) { \
            f16x8 a = *(const f16x8*)&abx[SX][kf]; \
            f16x8 b0 = *(const f16x8*)(smem + W12_OFF + (S)*8192 + kf*2048 +   0 + wb12); \
            f16x8 b1 = *(const f16x8*)(smem + W12_OFF + (S)*8192 + kf*2048 + 256 + wb12); \
            acc1[0] = __builtin_amdgcn_mfma_f32_16x16x32_f16(a, b0, acc1[0], 0,0,0); \
            acc1[1] = __builtin_amdgcn_mfma_f32_16x16x32_f16(a, b1, acc1[1], 0,0,0); \
        } } while(0)
    #define MF1S(S, SC) do { \
        _Pragma("unroll") for (int kf = 0; kf < 4; ++kf) { \
            f16x8 a = expand_fp8(abs_[SC][kf]); \
            f16x8 b0 = *(const f16x8*)(smem + W12_OFF + (S)*8192 + kf*2048 +   0 + wb12); \
            f16x8 b1 = *(const f16x8*)(smem + W12_OFF + (S)*8192 + kf*2048 + 256 + wb12); \
            acc1[0] = __builtin_amdgcn_mfma_f32_16x16x32_f16(a, b0, acc1[0], 0,0,0); \
            acc1[1] = __builtin_amdgcn_mfma_f32_16x16x32_f16(a, b1, acc1[1], 0,0,0); \
        } } while(0)
    #define MF2X(S, SX) do { \
        _Pragma("unroll") for (int kf = 0; kf < 4; ++kf) { \
            f16x8 a = *(const f16x8*)&abx[SX][kf]; \
            f16x8 b = *(const f16x8*)(smem + W3_OFF + (S)*4096 + kf*1024 + wb3); \
            acc2 = __builtin_amdgcn_mfma_f32_16x16x32_f16(a, b, acc2, 0,0,0); \
        } } while(0)
    #define MF2S(S, SC) do { \
        _Pragma("unroll") for (int kf = 0; kf < 4; ++kf) { \
            f16x8 a = expand_fp8(abs_[SC][kf]); \
            f16x8 b = *(const f16x8*)(smem + W3_OFF + (S)*4096 + kf*1024 + wb3); \
            acc2 = __builtin_amdgcn_mfma_f32_16x16x32_f16(a, b, acc2, 0,0,0); \
        } } while(0)

    for (int t = 0; t < T_; ++t) {
        const _Float16* xrt = xrow + (size_t)t * IN_;
        float u_reg[4];
        { // ---- P1: [u|r] = sigmoid([state|x_t] @ W12^T + b) ----
            ISSX(0); ISSX(1); ISSX(2); ISSX(3);
            ISSS(0); ISSS(1); ISSS(2); ISSS(3);
            f32x4 acc1[2] = {};
            WAITV(28); MF1X(8, 0);  ISSS(4);
            WAITV(28); MF1X(9, 1);  ISSS(5);
            WAITV(28); MF1X(10,2);  ISSS(6);
            WAITV(28); MF1X(11,3);  ISSS(7);
            WAITV(28); MF1S(0, 0);
            WAITV(24); MF1S(1, 1);
            WAITV(20); MF1S(2, 2);
            WAITV(16); MF1S(3, 3);
            WAITV(12); MF1S(4, 4);
            WAITV(8);  MF1S(5, 5);
            WAITV(4);  MF1S(6, 6);
            WAITV(0);  MF1S(7, 7);
            #pragma unroll
            for (int r = 0; r < 4; ++r) {
                u_reg[r] = sigmoidf_(acc1[0][r] + b1c);
                float rr = sigmoidf_(acc1[1][r] + b2c);
                st_coh_u8(rsh + ((size_t)(crow0 + r) << 10) + colU, to_fp8(rr * S_reg[r]));
            }
        }
        wave_barrier(flags, wgbase, j, l, ++it);
        { // ---- P2: ns = tanh([r*s|x_t] @ W3^T + b3); state update ----
            const int tn = (t < T_-1) ? t+1 : t;     // belta prefetch (clamped)
            unsigned bv[4];
            ISSX(0); ISSX(1); ISSX(2); ISSX(3);
            ISSR(0); ISSR(1); ISSR(2); ISSR(3);
            f32x4 acc2 = {};
            WAITV(28); MF2X(8, 0);  ISSR(4);
            WAITV(28); MF2X(9, 1);  ISSR(5);
            WAITV(28); MF2X(10,2);  ISSR(6);
            WAITV(28); MF2X(11,3);  ISSR(7);
            #pragma unroll
            for (int r = 0; r < 4; ++r)
                bv[r] = ld_u16(belh + ((size_t)(crow0 + r)*T_ + tn)*H_ + colU);
            WAITV(32); MF2S(0, 0);
            WAITV(28); MF2S(1, 1);
            WAITV(24); MF2S(2, 2);
            WAITV(20); MF2S(3, 3);
            WAITV(16); MF2S(4, 4);
            WAITV(12); MF2S(5, 5);
            WAITV(8);  MF2S(6, 6);
            WAITV(4);  MF2S(7, 7);
            WAITV(0);                                 // belta ready
            #pragma unroll
            for (int r = 0; r < 4; ++r) {
                float ns = tanhf_(acc2[r] + b3c);
                float sn = (1.f - u_reg[r])*S_reg[r] + u_reg[r]*ns;
                if (t < T_-1) {
                    unsigned short us = (unsigned short)bv[r];
                    float bel = (float)(*(_Float16*)&us);
                    float ss = bel * sn;
                    S_reg[r] = ss;
                    st_coh_u8(ssh + ((size_t)(crow0 + r) << 10) + colU, to_fp8(ss));
                } else {
                    pout[r] = sn * woc;
                }
            }
        }
        wave_barrier(flags, wgbase, j, l, ++it);
    }
    #undef MF1X
    #undef MF1S
    #undef MF2X
    #undef MF2S
    #undef ISSX
    #undef ISSS
    #undef ISSR
    // ---- final: sum pout over the block's 16 cols (ll), atomicAdd per row ----
    #pragma unroll
    for (int r = 0; r < 4; ++r) {
        float v = pout[r];
        v += __shfl_xor(v, 1, 64);
        v += __shfl_xor(v, 2, 64);
        v += __shfl_xor(v, 4, 64);
        v += __shfl_xor(v, 8, 64);
        if (ll == 0) atomicAdd(&outacc[crow0 + r], v);
    }
}

__global__ void finish_k(const float* __restrict__ acc, const float* __restrict__ bo,
                         float* __restrict__ out) {
    int i = threadIdx.x;
    out[i] = sigmoidf_(acc[i] + bo[0]);
}

extern "C" void kernel_launch(void* const* d_in, const int* in_sizes, int n_in,
                              void* d_out, int out_size, void* d_ws, size_t ws_size,
                              hipStream_t stream) {
    const float* x   = (const float*)d_in[0];
    const float* td  = (const float*)d_in[1];
    const float* Wb  = (const float*)d_in[2];
    const float* bb  = (const float*)d_in[3];
    const float* W1  = (const float*)d_in[4];
    const float* b1  = (const float*)d_in[5];
    const float* W2  = (const float*)d_in[6];
    const float* b2  = (const float*)d_in[7];
    const float* W3  = (const float*)d_in[8];
    const float* b3  = (const float*)d_in[9];
    const float* Wo  = (const float*)d_in[10];
    const float* bo  = (const float*)d_in[11];
    float* out = (float*)d_out;

    char* p = (char*)d_ws;
    auto carve = [&](size_t bytes) { char* r = p; p += (bytes + 255) & ~(size_t)255; return r; };
    int*           bar    = (int*)           carve(4096);            // 16 wave-groups x 64 flags
    float*         outacc = (float*)         carve(1024);            // 256 partial sums
    unsigned char* ssh    = (unsigned char*) carve((size_t)B_*H_);   // fp8 state exchange
    unsigned char* rsh    = (unsigned char*) carve((size_t)B_*H_);   // fp8 r*state exchange
    _Float16*      xh     = (_Float16*)      carve((size_t)NT*IN_*2);
    _Float16*      tdh    = (_Float16*)      carve((size_t)NT*IN_*2);
    _Float16*      belh   = (_Float16*)      carve((size_t)NT*H_*2);
    _Float16*      Wbh    = (_Float16*)      carve((size_t)H_*IN_*2);

    // zero: flags + outacc + ssh (contiguous at front of d_ws)
    size_t zbytes = 4096 + 1024 + (size_t)B_*H_;
    (void)hipMemsetAsync(bar, 0, zbytes, stream);

    const int thr = 256;
    int n8;
    n8 = NT*IN_/8;    cvt_f32_f16_k<<<(n8+thr-1)/thr, thr, 0, stream>>>(x,  xh,  n8);
    n8 = NT*IN_/8;    cvt_f32_f16_k<<<(n8+thr-1)/thr, thr, 0, stream>>>(td, tdh, n8);
    n8 = H_*IN_/8;    cvt_f32_f16_k<<<(n8+thr-1)/thr, thr, 0, stream>>>(Wb, Wbh, n8);

    belta_gemm_k<<<(NT/64)*(H_/128), 256, 0, stream>>>(tdh, Wbh, bb, belh);

    recur_k<<<256, 256, 0, stream>>>(xh, belh, W1, W2, W3, b1, b2, b3, Wo,
                                     ssh, rsh, bar, outacc);
    finish_k<<<1, 256, 0, stream>>>(outacc, bo, out);
}

// Round 13
// 2027.368 us; speedup vs baseline: 1.2566x; 1.2566x over previous
//
#include <hip/hip_runtime.h>
#include <hip/hip_fp16.h>

#define B_  256
#define T_  96
#define IN_ 512
#define H_  1024
#define K1  1536          // H + IN
#define NT  (B_*T_)       // 24576

// recur_k: 4 groups x 64 blocks; group owns 64 batch rows; block owns 16 cols
// of W1/W2/W3. Persistent LDS weights, K-MAJOR layout (conflict-free b128).
#define W12_OFF 0          // 98304 B
#define W3_OFF  98304      // 49152 B -> total 147456 B
typedef _Float16 f16x8 __attribute__((ext_vector_type(8)));
typedef float    f32x4 __attribute__((ext_vector_type(4)));
typedef float    f32x2 __attribute__((ext_vector_type(2)));

__device__ __forceinline__ float sigmoidf_(float z) { return 1.f/(1.f+__expf(-z)); }
__device__ __forceinline__ float tanhf_(float z)    { return 1.f - 2.f/(__expf(2.f*z)+1.f); }

// coherent (cross-XCD) access: bypass L1 + per-XCD L2
__device__ __forceinline__ uint2 ld_coh_b64(const void* p){
    uint2 r; asm volatile("global_load_dwordx2 %0, %1, off sc0 sc1" : "=&v"(r) : "v"(p)); return r;
}
__device__ __forceinline__ uint4 ld_b128(const void* p){
    uint4 r; asm volatile("global_load_dwordx4 %0, %1, off" : "=&v"(r) : "v"(p)); return r;
}
__device__ __forceinline__ unsigned ld_u16(const void* p){
    unsigned r; asm volatile("global_load_ushort %0, %1, off" : "=&v"(r) : "v"(p)); return r;
}
__device__ __forceinline__ void st_coh_u8(void* p, unsigned v){
    asm volatile("global_store_byte %0, %1, off sc0 sc1" :: "v"(p), "v"(v) : "memory");
}
#define WAITV(n) do { asm volatile("s_waitcnt vmcnt(" #n ")" ::: "memory"); \
                      __builtin_amdgcn_sched_barrier(0); } while(0)
__device__ __forceinline__ void waitv0_(){ asm volatile("s_waitcnt vmcnt(0)" ::: "memory"); }

// fp8 e4m3 helpers (OCP on gfx950)
__device__ __forceinline__ unsigned to_fp8(float x){
    return (unsigned)__builtin_amdgcn_cvt_pk_fp8_f32(x, x, 0, false) & 0xFFu;
}
__device__ __forceinline__ f16x8 expand_fp8(uint2 v){
    f32x2 p0 = __builtin_amdgcn_cvt_pk_f32_fp8(v.x, false);
    f32x2 p1 = __builtin_amdgcn_cvt_pk_f32_fp8(v.x, true);
    f32x2 p2 = __builtin_amdgcn_cvt_pk_f32_fp8(v.y, false);
    f32x2 p3 = __builtin_amdgcn_cvt_pk_f32_fp8(v.y, true);
    f16x8 o;
    o[0]=(_Float16)p0[0]; o[1]=(_Float16)p0[1];
    o[2]=(_Float16)p1[0]; o[3]=(_Float16)p1[1];
    o[4]=(_Float16)p2[0]; o[5]=(_Float16)p2[1];
    o[6]=(_Float16)p3[0]; o[7]=(_Float16)p3[1];
    return o;
}

// ---------------- prep: fp32 -> fp16 ----------------
__global__ void cvt_f32_f16_k(const float* __restrict__ src, _Float16* __restrict__ dst, int n8) {
    int i = blockIdx.x*blockDim.x + threadIdx.x;
    if (i >= n8) return;
    const float4* s = (const float4*)src;
    float4 a = s[2*(size_t)i], b = s[2*(size_t)i+1];
    f16x8 o;
    o[0]=(_Float16)a.x; o[1]=(_Float16)a.y; o[2]=(_Float16)a.z; o[3]=(_Float16)a.w;
    o[4]=(_Float16)b.x; o[5]=(_Float16)b.y; o[6]=(_Float16)b.z; o[7]=(_Float16)b.w;
    *(f16x8*)(dst + 8*(size_t)i) = o;
}

// ---------------- belta = exp(-relu(td @ Wb^T + bb)) ----------------
__global__ void __launch_bounds__(256) belta_gemm_k(const _Float16* __restrict__ td,
                                                    const _Float16* __restrict__ Wbh,
                                                    const float* __restrict__ bb,
                                                    _Float16* __restrict__ belta) {
    __shared__ _Float16 As[64][136];
    __shared__ _Float16 Bs[128][136];
    const int bid = blockIdx.x;
    const int mt = bid >> 3, nt = bid & 7;
    const int bt0 = mt*64, h0 = nt*128;
    const int tid = threadIdx.x;
    const int w = tid >> 6, l = tid & 63;
    const int wm = (w>>1)*32, wn = (w&1)*64;
    f32x4 acc[2][4] = {};
    for (int kc = 0; kc < 4; ++kc) {
        const int kbase = kc*128;
        #pragma unroll
        for (int p = 0; p < 4; ++p) {
            int unit = tid + 256*p; int r = unit>>4, cu = unit&15;
            *(uint4*)&As[r][cu*8] = *(const uint4*)(td + (size_t)(bt0+r)*IN_ + kbase + cu*8);
        }
        #pragma unroll
        for (int p = 0; p < 8; ++p) {
            int unit = tid + 256*p; int r = unit>>4, cu = unit&15;
            *(uint4*)&Bs[r][cu*8] = *(const uint4*)(Wbh + (size_t)(h0+r)*IN_ + kbase + cu*8);
        }
        __syncthreads();
        #pragma unroll
        for (int ks = 0; ks < 4; ++ks) {
            const int kk = ks*32 + (l>>4)*8;
            f16x8 a0 = *(const f16x8*)&As[wm +      (l&15)][kk];
            f16x8 a1 = *(const f16x8*)&As[wm + 16 + (l&15)][kk];
            #pragma unroll
            for (int ni = 0; ni < 4; ++ni) {
                f16x8 b = *(const f16x8*)&Bs[wn + ni*16 + (l&15)][kk];
                acc[0][ni] = __builtin_amdgcn_mfma_f32_16x16x32_f16(a0, b, acc[0][ni], 0,0,0);
                acc[1][ni] = __builtin_amdgcn_mfma_f32_16x16x32_f16(a1, b, acc[1][ni], 0,0,0);
            }
        }
        __syncthreads();
    }
    #pragma unroll
    for (int mi = 0; mi < 2; ++mi)
    #pragma unroll
    for (int ni = 0; ni < 4; ++ni)
    #pragma unroll
    for (int r = 0; r < 4; ++r) {
        int m_l = wm + mi*16 + (l>>4)*4 + r;
        int n_l = wn + ni*16 + (l&15);
        int bt = bt0 + m_l, h = h0 + n_l;
        float z = acc[mi][ni][r] + bb[h];
        belta[(size_t)bt*H_ + h] = (_Float16)__expf(-fmaxf(z, 0.f));
    }
}

// ---------------- group barrier (64 blocks, relaxed agent atomics) ----------------
__device__ __forceinline__ void group_barrier(int* flags, int gbase, int j, int it) {
    waitv0_();                 // drain inline-asm stores before publishing
    __syncthreads();
    if (threadIdx.x == 0)
        __hip_atomic_store(&flags[gbase + j], it, __ATOMIC_RELAXED, __HIP_MEMORY_SCOPE_AGENT);
    for (;;) {
        int v = __hip_atomic_load(&flags[gbase + (threadIdx.x & 63)],
                                  __ATOMIC_RELAXED, __HIP_MEMORY_SCOPE_AGENT);
        if (__syncthreads_count(v < it) == 0) break;
        __builtin_amdgcn_s_sleep(2);
    }
}

// ---------------- recurrent scan: LDS f16 weights + fp8 exchange, all-upfront issue ----------------
__global__ void __launch_bounds__(256, 1) recur_k(
    const _Float16* __restrict__ xh,     // (B,T,IN) fp16, plain cached
    const _Float16* __restrict__ belh,   // (B,T,H) fp16, plain cached
    const float* __restrict__ W1, const float* __restrict__ W2, const float* __restrict__ W3,
    const float* __restrict__ b1, const float* __restrict__ b2, const float* __restrict__ b3,
    const float* __restrict__ Wo,
    unsigned char* __restrict__ ssh,     // (256,1024) fp8 scaled state — coherent exchange
    unsigned char* __restrict__ rsh,     // (256,1024) fp8 r*state — coherent exchange
    int* flags, float* __restrict__ outacc)
{
    __shared__ __align__(16) char smem[147456];
    const int bid = blockIdx.x, tid = threadIdx.x;
    const int g = bid >> 6, j = bid & 63;
    const int gbase = g*64, grow0 = g*64;
    const int w = tid >> 6;              // wave = M-fragment index (rows w*16..w*16+15)
    const int l = tid & 63;
    const int lh = l >> 4;               // k-slot
    const int ll = l & 15;               // A-row / B-row within fragment

    // ---- prologue: weight slices -> LDS, K-MAJOR f16 (f32->f16) ----
    for (int u = tid; u < 32*192; u += 256) {        // W12: 32 rows x 192 k8-slots
        int row = u / 192, slot = u - row*192;
        const float* src = (row < 16) ? (W1 + ((size_t)(16*j + row))*K1 + slot*8)
                                      : (W2 + ((size_t)(16*j + row-16))*K1 + slot*8);
        float4 f0 = *(const float4*)src, f1 = *(const float4*)(src+4);
        f16x8 h;
        h[0]=(_Float16)f0.x; h[1]=(_Float16)f0.y; h[2]=(_Float16)f0.z; h[3]=(_Float16)f0.w;
        h[4]=(_Float16)f1.x; h[5]=(_Float16)f1.y; h[6]=(_Float16)f1.z; h[7]=(_Float16)f1.w;
        *(f16x8*)(smem + W12_OFF + (slot*32 + row)*16) = h;
    }
    for (int u = tid; u < 16*192; u += 256) {        // W3: 16 rows x 192 k8-slots
        int row = u / 192, slot = u - row*192;
        const float* src = W3 + ((size_t)(16*j + row))*K1 + slot*8;
        float4 f0 = *(const float4*)src, f1 = *(const float4*)(src+4);
        f16x8 h;
        h[0]=(_Float16)f0.x; h[1]=(_Float16)f0.y; h[2]=(_Float16)f0.z; h[3]=(_Float16)f0.w;
        h[4]=(_Float16)f1.x; h[5]=(_Float16)f1.y; h[6]=(_Float16)f1.z; h[7]=(_Float16)f1.w;
        *(f16x8*)(smem + W3_OFF + (slot*16 + row)*16) = h;
    }
    __syncthreads();

    const int colU = (j<<4) + ll;                    // owned output column
    const float b1c = b1[colU], b2c = b2[colU], b3c = b3[colU];
    const float woc = Wo[colU];
    const int wb12 = lh*512 + ll*16;                 // per-lane LDS byte offsets
    const int wb3  = lh*256 + ll*16;

    // per-lane A-load bases: row = grow0 + w*16 + ll, k-offset lh*8
    const unsigned char* srow_s = ssh + ((size_t)(grow0 + w*16 + ll) << 10) + lh*8;
    const unsigned char* srow_r = rsh + ((size_t)(grow0 + w*16 + ll) << 10) + lh*8;
    const _Float16* xrow = xh + (size_t)(grow0 + w*16 + ll) * T_ * IN_ + lh*8;
    const int crow0 = grow0 + w*16 + lh*4;           // epilogue rows (+r)

    float S_reg[4] = {0.f,0.f,0.f,0.f};
    float pout[4]  = {0.f,0.f,0.f,0.f};
    uint4 abx[4][4];                                 // x frags (f16), 64 VGPR — live P1+P2
    uint2 abs_[8][4];                                // coherent fp8 frags, 64 VGPR
    int it = 0;

    // issue macros
    #define ISSX(SX) do { _Pragma("unroll") for (int kf=0;kf<4;++kf) \
        abx[SX][kf] = ld_b128(xrt + (SX)*128 + kf*32); } while(0)
    #define ISSS(SC) do { _Pragma("unroll") for (int kf=0;kf<4;++kf) \
        abs_[SC][kf] = ld_coh_b64(srow_s + (SC)*128 + kf*32); } while(0)
    #define ISSR(SC) do { _Pragma("unroll") for (int kf=0;kf<4;++kf) \
        abs_[SC][kf] = ld_coh_b64(srow_r + (SC)*128 + kf*32); } while(0)
    // consume: S = absolute weight k-section (0..11)
    #define MF1X(S, SX) do { \
        _Pragma("unroll") for (int kf = 0; kf < 4; ++kf) { \
            f16x8 a = *(const f16x8*)&abx[SX][kf]; \
            f16x8 b0 = *(const f16x8*)(smem + W12_OFF + (S)*8192 + kf*2048 +   0 + wb12); \
            f16x8 b1 = *(const f16x8*)(smem + W12_OFF + (S)*8192 + kf*2048 + 256 + wb12); \
            acc1[0] = __builtin_amdgcn_mfma_f32_16x16x32_f16(a, b0, acc1[0], 0,0,0); \
            acc1[1] = __builtin_amdgcn_mfma_f32_16x16x32_f16(a, b1, acc1[1], 0,0,0); \
        } } while(0)
    #define MF1S(S, SC) do { \
        _Pragma("unroll") for (int kf = 0; kf < 4; ++kf) { \
            f16x8 a = expand_fp8(abs_[SC][kf]); \
            f16x8 b0 = *(const f16x8*)(smem + W12_OFF + (S)*8192 + kf*2048 +   0 + wb12); \
            f16x8 b1 = *(const f16x8*)(smem + W12_OFF + (S)*8192 + kf*2048 + 256 + wb12); \
            acc1[0] = __builtin_amdgcn_mfma_f32_16x16x32_f16(a, b0, acc1[0], 0,0,0); \
            acc1[1] = __builtin_amdgcn_mfma_f32_16x16x32_f16(a, b1, acc1[1], 0,0,0); \
        } } while(0)
    #define MF2X(S, SX) do { \
        _Pragma("unroll") for (int kf = 0; kf < 4; ++kf) { \
            f16x8 a = *(const f16x8*)&abx[SX][kf]; \
            f16x8 b = *(const f16x8*)(smem + W3_OFF + (S)*4096 + kf*1024 + wb3); \
            acc2 = __builtin_amdgcn_mfma_f32_16x16x32_f16(a, b, acc2, 0,0,0); \
        } } while(0)
    #define MF2S(S, SC) do { \
        _Pragma("unroll") for (int kf = 0; kf < 4; ++kf) { \
            f16x8 a = expand_fp8(abs_[SC][kf]); \
            f16x8 b = *(const f16x8*)(smem + W3_OFF + (S)*4096 + kf*1024 + wb3); \
            acc2 = __builtin_amdgcn_mfma_f32_16x16x32_f16(a, b, acc2, 0,0,0); \
        } } while(0)

    for (int t = 0; t < T_; ++t) {
        const _Float16* xrt = xrow + (size_t)t * IN_;
        float u_reg[4];
        { // ---- P1: [u|r] = sigmoid([state|x_t] @ W12^T + b) ----
            // ALL loads upfront: 16 x (plain) + 32 coherent = 48 in flight
            ISSX(0); ISSX(1); ISSX(2); ISSX(3);
            ISSS(0); ISSS(1); ISSS(2); ISSS(3);
            ISSS(4); ISSS(5); ISSS(6); ISSS(7);
            f32x4 acc1[2] = {};
            WAITV(44); MF1X(8, 0);
            WAITV(40); MF1X(9, 1);
            WAITV(36); MF1X(10,2);
            WAITV(32); MF1X(11,3);
            WAITV(28); MF1S(0, 0);
            WAITV(24); MF1S(1, 1);
            WAITV(20); MF1S(2, 2);
            WAITV(16); MF1S(3, 3);
            WAITV(12); MF1S(4, 4);
            WAITV(8);  MF1S(5, 5);
            WAITV(4);  MF1S(6, 6);
            WAITV(0);  MF1S(7, 7);
            #pragma unroll
            for (int r = 0; r < 4; ++r) {
                u_reg[r] = sigmoidf_(acc1[0][r] + b1c);
                float rr = sigmoidf_(acc1[1][r] + b2c);
                st_coh_u8(rsh + ((size_t)(crow0 + r) << 10) + colU, to_fp8(rr * S_reg[r]));
            }
        }
        group_barrier(flags, gbase, j, ++it);
        { // ---- P2: ns = tanh([r*s|x_t] @ W3^T + b3); x frags REUSED from P1 regs ----
            const int tn = (t < T_-1) ? t+1 : t;     // belta prefetch (clamped)
            unsigned bv[4];
            ISSR(0); ISSR(1); ISSR(2); ISSR(3);
            ISSR(4); ISSR(5); ISSR(6); ISSR(7);      // 32 coherent in flight
            #pragma unroll
            for (int r = 0; r < 4; ++r)
                bv[r] = ld_u16(belh + ((size_t)(crow0 + r)*T_ + tn)*H_ + colU);
            f32x4 acc2 = {};
            MF2X(8, 0); MF2X(9, 1); MF2X(10,2); MF2X(11,3);   // free cover (reg-resident)
            WAITV(32); MF2S(0, 0);
            WAITV(28); MF2S(1, 1);
            WAITV(24); MF2S(2, 2);
            WAITV(20); MF2S(3, 3);
            WAITV(16); MF2S(4, 4);
            WAITV(12); MF2S(5, 5);
            WAITV(8);  MF2S(6, 6);
            WAITV(4);  MF2S(7, 7);
            WAITV(0);                                 // belta ready
            #pragma unroll
            for (int r = 0; r < 4; ++r) {
                float ns = tanhf_(acc2[r] + b3c);
                float sn = (1.f - u_reg[r])*S_reg[r] + u_reg[r]*ns;
                if (t < T_-1) {
                    unsigned short us = (unsigned short)bv[r];
                    float bel = (float)(*(_Float16*)&us);
                    float ss = bel * sn;
                    S_reg[r] = ss;
                    st_coh_u8(ssh + ((size_t)(crow0 + r) << 10) + colU, to_fp8(ss));
                } else {
                    pout[r] = sn * woc;
                }
            }
        }
        group_barrier(flags, gbase, j, ++it);
    }
    #undef MF1X
    #undef MF1S
    #undef MF2X
    #undef MF2S
    #undef ISSX
    #undef ISSS
    #undef ISSR
    // ---- final: sum pout over the block's 16 cols (ll), atomicAdd per row ----
    #pragma unroll
    for (int r = 0; r < 4; ++r) {
        float v = pout[r];
        v += __shfl_xor(v, 1, 64);
        v += __shfl_xor(v, 2, 64);
        v += __shfl_xor(v, 4, 64);
        v += __shfl_xor(v, 8, 64);
        if (ll == 0) atomicAdd(&outacc[crow0 + r], v);
    }
}

__global__ void finish_k(const float* __restrict__ acc, const float* __restrict__ bo,
                         float* __restrict__ out) {
    int i = threadIdx.x;
    out[i] = sigmoidf_(acc[i] + bo[0]);
}

extern "C" void kernel_launch(void* const* d_in, const int* in_sizes, int n_in,
                              void* d_out, int out_size, void* d_ws, size_t ws_size,
                              hipStream_t stream) {
    const float* x   = (const float*)d_in[0];
    const float* td  = (const float*)d_in[1];
    const float* Wb  = (const float*)d_in[2];
    const float* bb  = (const float*)d_in[3];
    const float* W1  = (const float*)d_in[4];
    const float* b1  = (const float*)d_in[5];
    const float* W2  = (const float*)d_in[6];
    const float* b2  = (const float*)d_in[7];
    const float* W3  = (const float*)d_in[8];
    const float* b3  = (const float*)d_in[9];
    const float* Wo  = (const float*)d_in[10];
    const float* bo  = (const float*)d_in[11];
    float* out = (float*)d_out;

    char* p = (char*)d_ws;
    auto carve = [&](size_t bytes) { char* r = p; p += (bytes + 255) & ~(size_t)255; return r; };
    int*           bar    = (int*)           carve(1024);            // 256 flags
    float*         outacc = (float*)         carve(1024);            // 256 partial sums
    unsigned char* ssh    = (unsigned char*) carve((size_t)B_*H_);   // fp8 state exchange
    unsigned char* rsh    = (unsigned char*) carve((size_t)B_*H_);   // fp8 r*state exchange
    _Float16*      xh     = (_Float16*)      carve((size_t)NT*IN_*2);
    _Float16*      tdh    = (_Float16*)      carve((size_t)NT*IN_*2);
    _Float16*      belh   = (_Float16*)      carve((size_t)NT*H_*2);
    _Float16*      Wbh    = (_Float16*)      carve((size_t)H_*IN_*2);

    // zero: flags + outacc + ssh (contiguous at front of d_ws)
    size_t zbytes = 1024 + 1024 + (size_t)B_*H_;
    (void)hipMemsetAsync(bar, 0, zbytes, stream);

    const int thr = 256;
    int n8;
    n8 = NT*IN_/8;    cvt_f32_f16_k<<<(n8+thr-1)/thr, thr, 0, stream>>>(x,  xh,  n8);
    n8 = NT*IN_/8;    cvt_f32_f16_k<<<(n8+thr-1)/thr, thr, 0, stream>>>(td, tdh, n8);
    n8 = H_*IN_/8;    cvt_f32_f16_k<<<(n8+thr-1)/thr, thr, 0, stream>>>(Wb, Wbh, n8);

    belta_gemm_k<<<(NT/64)*(H_/128), 256, 0, stream>>>(tdh, Wbh, bb, belh);

    recur_k<<<256, 256, 0, stream>>>(xh, belh, W1, W2, W3, b1, b2, b3, Wo,
                                     ssh, rsh, bar, outacc);
    finish_k<<<1, 256, 0, stream>>>(outacc, bo, out);
}

// Round 14
// 1488.823 us; speedup vs baseline: 1.7112x; 1.3617x over previous
//
#include <hip/hip_runtime.h>
#include <hip/hip_fp16.h>

#define B_  256
#define T_  96
#define IN_ 512
#define H_  1024
#define K1  1536          // H + IN
#define NT  (B_*T_)       // 24576

// recur_k: 8 XCD-groups x 32 blocks (group discovered at runtime via XCC_ID).
// Group owns 32 batch rows; block owns 32 cols of W1/W2/W3 (state-part only;
// x-part precomputed into Xc12/Xc3). LDS: W12s fp8 + W3s f16, k-major.
#define W12S_OFF 0        // fp8: ((k8*64 + row))*8, row 0-31=W1, 32-63=W2 ; 65536 B
#define W3S_OFF  65536    // f16: ((k8*32 + row))*16 ; 65536 B -> total 131072 B

typedef _Float16 f16x8 __attribute__((ext_vector_type(8)));
typedef float    f32x4 __attribute__((ext_vector_type(4)));
typedef float    f32x2 __attribute__((ext_vector_type(2)));

__device__ __forceinline__ float sigmoidf_(float z) { return 1.f/(1.f+__expf(-z)); }
__device__ __forceinline__ float tanhf_(float z)    { return 1.f - 2.f/(__expf(2.f*z)+1.f); }

// sc0 = bypass L1, served by this XCD's L2 (group members share one L2)
__device__ __forceinline__ uint4 ld_l2_b128(const void* p){
    uint4 r; asm volatile("global_load_dwordx4 %0, %1, off sc0" : "=&v"(r) : "v"(p)); return r;
}
__device__ __forceinline__ unsigned ld_u16p(const void* p){
    unsigned r; asm volatile("global_load_ushort %0, %1, off" : "=&v"(r) : "v"(p)); return r;
}
__device__ __forceinline__ void st_l2_u16(void* p, unsigned v){
    asm volatile("global_store_short %0, %1, off sc0" :: "v"(p), "v"(v) : "memory");
}
#define WAITV(n) do { asm volatile("s_waitcnt vmcnt(" #n ")" ::: "memory"); \
                      __builtin_amdgcn_sched_barrier(0); } while(0)
__device__ __forceinline__ void waitv0_(){ asm volatile("s_waitcnt vmcnt(0)" ::: "memory"); }

__device__ __forceinline__ f16x8 expand_fp8(uint2 v){
    f32x2 p0 = __builtin_amdgcn_cvt_pk_f32_fp8(v.x, false);
    f32x2 p1 = __builtin_amdgcn_cvt_pk_f32_fp8(v.x, true);
    f32x2 p2 = __builtin_amdgcn_cvt_pk_f32_fp8(v.y, false);
    f32x2 p3 = __builtin_amdgcn_cvt_pk_f32_fp8(v.y, true);
    f16x8 o;
    o[0]=(_Float16)p0[0]; o[1]=(_Float16)p0[1];
    o[2]=(_Float16)p1[0]; o[3]=(_Float16)p1[1];
    o[4]=(_Float16)p2[0]; o[5]=(_Float16)p2[1];
    o[6]=(_Float16)p3[0]; o[7]=(_Float16)p3[1];
    return o;
}

// ---------------- prep: fp32 -> fp16 ----------------
__global__ void cvt_f32_f16_k(const float* __restrict__ src, _Float16* __restrict__ dst, int n8) {
    int i = blockIdx.x*blockDim.x + threadIdx.x;
    if (i >= n8) return;
    const float4* s = (const float4*)src;
    float4 a = s[2*(size_t)i], b = s[2*(size_t)i+1];
    f16x8 o;
    o[0]=(_Float16)a.x; o[1]=(_Float16)a.y; o[2]=(_Float16)a.z; o[3]=(_Float16)a.w;
    o[4]=(_Float16)b.x; o[5]=(_Float16)b.y; o[6]=(_Float16)b.z; o[7]=(_Float16)b.w;
    *(f16x8*)(dst + 8*(size_t)i) = o;
}

// pack x-part (cols 1024..1536) of a weight matrix to f16 (rows x 512)
__global__ void pack_xpart_k(const float* __restrict__ W, _Float16* __restrict__ dst, int n8) {
    int i = blockIdx.x*blockDim.x + threadIdx.x;
    if (i >= n8) return;
    int row = i >> 6, slot = i & 63;
    const float* src = W + (size_t)row*K1 + 1024 + slot*8;
    float4 a = *(const float4*)src, b = *(const float4*)(src+4);
    f16x8 o;
    o[0]=(_Float16)a.x; o[1]=(_Float16)a.y; o[2]=(_Float16)a.z; o[3]=(_Float16)a.w;
    o[4]=(_Float16)b.x; o[5]=(_Float16)b.y; o[6]=(_Float16)b.z; o[7]=(_Float16)b.w;
    *(f16x8*)(dst + (size_t)row*512 + slot*8) = o;
}

// ---------------- belta = exp(-relu(td @ Wb^T + bb)) ----------------
__global__ void __launch_bounds__(256) belta_gemm_k(const _Float16* __restrict__ td,
                                                    const _Float16* __restrict__ Wbh,
                                                    const float* __restrict__ bb,
                                                    _Float16* __restrict__ belta) {
    __shared__ _Float16 As[64][136];
    __shared__ _Float16 Bs[128][136];
    const int bid = blockIdx.x;
    const int mt = bid >> 3, nt = bid & 7;
    const int bt0 = mt*64, h0 = nt*128;
    const int tid = threadIdx.x;
    const int w = tid >> 6, l = tid & 63;
    const int wm = (w>>1)*32, wn = (w&1)*64;
    f32x4 acc[2][4] = {};
    for (int kc = 0; kc < 4; ++kc) {
        const int kbase = kc*128;
        #pragma unroll
        for (int p = 0; p < 4; ++p) {
            int unit = tid + 256*p; int r = unit>>4, cu = unit&15;
            *(uint4*)&As[r][cu*8] = *(const uint4*)(td + (size_t)(bt0+r)*IN_ + kbase + cu*8);
        }
        #pragma unroll
        for (int p = 0; p < 8; ++p) {
            int unit = tid + 256*p; int r = unit>>4, cu = unit&15;
            *(uint4*)&Bs[r][cu*8] = *(const uint4*)(Wbh + (size_t)(h0+r)*IN_ + kbase + cu*8);
        }
        __syncthreads();
        #pragma unroll
        for (int ks = 0; ks < 4; ++ks) {
            const int kk = ks*32 + (l>>4)*8;
            f16x8 a0 = *(const f16x8*)&As[wm +      (l&15)][kk];
            f16x8 a1 = *(const f16x8*)&As[wm + 16 + (l&15)][kk];
            #pragma unroll
            for (int ni = 0; ni < 4; ++ni) {
                f16x8 b = *(const f16x8*)&Bs[wn + ni*16 + (l&15)][kk];
                acc[0][ni] = __builtin_amdgcn_mfma_f32_16x16x32_f16(a0, b, acc[0][ni], 0,0,0);
                acc[1][ni] = __builtin_amdgcn_mfma_f32_16x16x32_f16(a1, b, acc[1][ni], 0,0,0);
            }
        }
        __syncthreads();
    }
    #pragma unroll
    for (int mi = 0; mi < 2; ++mi)
    #pragma unroll
    for (int ni = 0; ni < 4; ++ni)
    #pragma unroll
    for (int r = 0; r < 4; ++r) {
        int m_l = wm + mi*16 + (l>>4)*4 + r;
        int n_l = wn + ni*16 + (l&15);
        int bt = bt0 + m_l, h = h0 + n_l;
        float z = acc[mi][ni][r] + bb[h];
        belta[(size_t)bt*H_ + h] = (_Float16)__expf(-fmaxf(z, 0.f));
    }
}

// ---------------- Xc = x @ Wx^T + bias (f16 out), N = 2048 or 1024 ----------------
__global__ void __launch_bounds__(256) xc_gemm_k(const _Float16* __restrict__ A,
                                                 const _Float16* __restrict__ Bh,
                                                 const float* __restrict__ bias0,
                                                 const float* __restrict__ bias1,
                                                 _Float16* __restrict__ out,
                                                 int N, int nblk) {
    __shared__ _Float16 As[64][136];
    __shared__ _Float16 Bs[128][136];
    const int bid = blockIdx.x;
    const int mt = bid / nblk, nt = bid - mt*nblk;
    const int bt0 = mt*64, h0 = nt*128;
    const int tid = threadIdx.x;
    const int w = tid >> 6, l = tid & 63;
    const int wm = (w>>1)*32, wn = (w&1)*64;
    f32x4 acc[2][4] = {};
    for (int kc = 0; kc < 4; ++kc) {
        const int kbase = kc*128;
        #pragma unroll
        for (int p = 0; p < 4; ++p) {
            int unit = tid + 256*p; int r = unit>>4, cu = unit&15;
            *(uint4*)&As[r][cu*8] = *(const uint4*)(A + (size_t)(bt0+r)*IN_ + kbase + cu*8);
        }
        #pragma unroll
        for (int p = 0; p < 8; ++p) {
            int unit = tid + 256*p; int r = unit>>4, cu = unit&15;
            *(uint4*)&Bs[r][cu*8] = *(const uint4*)(Bh + (size_t)(h0+r)*IN_ + kbase + cu*8);
        }
        __syncthreads();
        #pragma unroll
        for (int ks = 0; ks < 4; ++ks) {
            const int kk = ks*32 + (l>>4)*8;
            f16x8 a0 = *(const f16x8*)&As[wm +      (l&15)][kk];
            f16x8 a1 = *(const f16x8*)&As[wm + 16 + (l&15)][kk];
            #pragma unroll
            for (int ni = 0; ni < 4; ++ni) {
                f16x8 b = *(const f16x8*)&Bs[wn + ni*16 + (l&15)][kk];
                acc[0][ni] = __builtin_amdgcn_mfma_f32_16x16x32_f16(a0, b, acc[0][ni], 0,0,0);
                acc[1][ni] = __builtin_amdgcn_mfma_f32_16x16x32_f16(a1, b, acc[1][ni], 0,0,0);
            }
        }
        __syncthreads();
    }
    #pragma unroll
    for (int mi = 0; mi < 2; ++mi)
    #pragma unroll
    for (int ni = 0; ni < 4; ++ni)
    #pragma unroll
    for (int r = 0; r < 4; ++r) {
        int m_l = wm + mi*16 + (l>>4)*4 + r;
        int n_l = wn + ni*16 + (l&15);
        int bt = bt0 + m_l, h = h0 + n_l;
        float z = acc[mi][ni][r] + (h < 1024 ? bias0[h] : bias1[h-1024]);
        out[(size_t)bt*N + h] = (_Float16)z;
    }
}

// ---------------- XCD-local barrier (32 blocks sharing one L2) ----------------
__device__ __forceinline__ void group_barrier32(int* flags, int gbase, int j, int it) {
    waitv0_();                 // sc0 stores committed to L2 before publishing
    __syncthreads();
    if (threadIdx.x == 0)
        __hip_atomic_store(&flags[gbase + j], it, __ATOMIC_RELAXED, __HIP_MEMORY_SCOPE_AGENT);
    for (;;) {
        int v = __hip_atomic_load(&flags[gbase + (threadIdx.x & 31)],
                                  __ATOMIC_RELAXED, __HIP_MEMORY_SCOPE_AGENT);
        if (__syncthreads_count(v < it) == 0) break;
        __builtin_amdgcn_s_sleep(1);
    }
}

// ---------------- recurrent scan: XCD-local, K=1024 state-only ----------------
__global__ void __launch_bounds__(256, 1) recur_k(
    const _Float16* __restrict__ belh,   // (B,T,H)
    const float* __restrict__ W1, const float* __restrict__ W2, const float* __restrict__ W3,
    const _Float16* __restrict__ xc12,   // (B*T, 2048): x@W12x^T + b (u|r)
    const _Float16* __restrict__ xc3,    // (B*T, 1024): x@W3x^T + b3
    const float* __restrict__ Wo,
    _Float16* __restrict__ ssh,          // (256,1024) f16 scaled state — L2 exchange
    _Float16* __restrict__ rsh,          // (256,1024) f16 r*state — L2 exchange
    int* flags, int* claim, float* __restrict__ outacc)
{
    __shared__ __align__(16) char smem[131072];
    __shared__ int sh_gid[2];
    const int tid = threadIdx.x;
    if (tid == 0) {
        int xcd;
        asm volatile("s_getreg_b32 %0, hwreg(HW_REG_XCC_ID)" : "=s"(xcd));
        xcd &= 7;
        sh_gid[0] = xcd;
        sh_gid[1] = atomicAdd(&claim[xcd], 1) & 31;
    }
    __syncthreads();
    const int g = sh_gid[0], j = sh_gid[1];
    const int gbase = g*64, grow0 = g*32;
    const int w = tid >> 6, l = tid & 63;
    const int lh = l >> 4, ll = l & 15;
    const int mi = w >> 1, nc = w & 1;   // wave = (M-frag, N-half)

    // ---- LDS fill: W12 state-part fp8 (64 rows x 128 k8-slots, k-major) ----
    for (int u = tid; u < 64*128; u += 256) {
        int row = u >> 7, slot = u & 127;
        const float* src = (row < 32 ? W1 + (size_t)(32*j + row)*K1
                                     : W2 + (size_t)(32*j + row-32)*K1) + slot*8;
        unsigned lo = 0, hi = 0;
        lo = __builtin_amdgcn_cvt_pk_fp8_f32(src[0], src[1], lo, false);
        lo = __builtin_amdgcn_cvt_pk_fp8_f32(src[2], src[3], lo, true);
        hi = __builtin_amdgcn_cvt_pk_fp8_f32(src[4], src[5], hi, false);
        hi = __builtin_amdgcn_cvt_pk_fp8_f32(src[6], src[7], hi, true);
        uint2 o; o.x = lo; o.y = hi;
        *(uint2*)(smem + W12S_OFF + ((size_t)slot*64 + row)*8) = o;
    }
    // ---- W3 state-part f16 (32 rows x 128 k8-slots, k-major) ----
    for (int u = tid; u < 32*128; u += 256) {
        int row = u >> 7, slot = u & 127;
        const float* src = W3 + (size_t)(32*j + row)*K1 + slot*8;
        float4 f0 = *(const float4*)src, f1 = *(const float4*)(src+4);
        f16x8 h;
        h[0]=(_Float16)f0.x; h[1]=(_Float16)f0.y; h[2]=(_Float16)f0.z; h[3]=(_Float16)f0.w;
        h[4]=(_Float16)f1.x; h[5]=(_Float16)f1.y; h[6]=(_Float16)f1.z; h[7]=(_Float16)f1.w;
        *(f16x8*)(smem + W3S_OFF + ((size_t)slot*32 + row)*16) = h;
    }
    __syncthreads();

    const int colU = j*32 + nc*16 + ll;              // owned output column
    const float woc = Wo[colU];
    const int crow0 = grow0 + mi*16 + lh*4;          // epilogue rows (+r)

    // per-lane A bases (f16 exchange): row = grow0 + mi*16 + ll
    const _Float16* srow_s = ssh + ((size_t)(grow0 + mi*16 + ll) << 10) + lh*8;
    const _Float16* srow_r = rsh + ((size_t)(grow0 + mi*16 + ll) << 10) + lh*8;

    float S_reg[4] = {0.f,0.f,0.f,0.f};
    float pout[4]  = {0.f,0.f,0.f,0.f};
    uint4 ab[32];                                    // A frags (128 VGPR), static idx
    int it = 0;

    #define ISSA(PTR) do { _Pragma("unroll") for (int k2 = 0; k2 < 32; ++k2) \
        ab[k2] = ld_l2_b128((PTR) + k2*32); } while(0)
    #define SEC1(S) do { \
        _Pragma("unroll") for (int kf = 0; kf < 4; ++kf) { \
            const int kx = (S)*4 + kf; \
            f16x8 a = *(const f16x8*)&ab[kx]; \
            uint2 bu = *(const uint2*)(smem + W12S_OFF + ((kx*4+lh)*64 + nc*16 + ll)*8); \
            uint2 br = *(const uint2*)(smem + W12S_OFF + ((kx*4+lh)*64 + 32 + nc*16 + ll)*8); \
            accu = __builtin_amdgcn_mfma_f32_16x16x32_f16(a, expand_fp8(bu), accu, 0,0,0); \
            accr = __builtin_amdgcn_mfma_f32_16x16x32_f16(a, expand_fp8(br), accr, 0,0,0); \
        } } while(0)
    #define SEC2(S) do { \
        _Pragma("unroll") for (int kf = 0; kf < 4; ++kf) { \
            const int kx = (S)*4 + kf; \
            f16x8 a = *(const f16x8*)&ab[kx]; \
            f16x8 b = *(const f16x8*)(smem + W3S_OFF + ((kx*4+lh)*32 + nc*16 + ll)*16); \
            acc2 = __builtin_amdgcn_mfma_f32_16x16x32_f16(a, b, acc2, 0,0,0); \
        } } while(0)

    for (int t = 0; t < T_; ++t) {
        float u_reg[4];
        { // ---- P1: u,r = sigmoid(s @ W12s^T + Xc12) ----
            unsigned xcu[4], xcr[4];
            #pragma unroll
            for (int r = 0; r < 4; ++r)
                xcu[r] = ld_u16p(xc12 + ((size_t)(crow0 + r)*T_ + t)*2048 + colU);
            #pragma unroll
            for (int r = 0; r < 4; ++r)
                xcr[r] = ld_u16p(xc12 + ((size_t)(crow0 + r)*T_ + t)*2048 + 1024 + colU);
            ISSA(srow_s);                            // 8 u16 + 32 b128 in flight
            f32x4 accu = {}, accr = {};
            WAITV(28); SEC1(0);
            WAITV(24); SEC1(1);
            WAITV(20); SEC1(2);
            WAITV(16); SEC1(3);
            WAITV(12); SEC1(4);
            WAITV(8);  SEC1(5);
            WAITV(4);  SEC1(6);
            WAITV(0);  SEC1(7);
            #pragma unroll
            for (int r = 0; r < 4; ++r) {
                unsigned short uu16 = (unsigned short)xcu[r], rr16 = (unsigned short)xcr[r];
                float uu = sigmoidf_(accu[r] + (float)(*(_Float16*)&uu16));
                float rr = sigmoidf_(accr[r] + (float)(*(_Float16*)&rr16));
                u_reg[r] = uu;
                _Float16 hv = (_Float16)(rr * S_reg[r]);
                st_l2_u16(rsh + ((size_t)(crow0 + r) << 10) + colU,
                          (unsigned)*(unsigned short*)&hv);
            }
        }
        group_barrier32(flags, gbase, j, ++it);
        { // ---- P2: ns = tanh((r*s) @ W3s^T + Xc3); state update ----
            const int tn = (t < T_-1) ? t+1 : t;
            unsigned xc3v[4], bv[4];
            #pragma unroll
            for (int r = 0; r < 4; ++r)
                xc3v[r] = ld_u16p(xc3 + ((size_t)(crow0 + r)*T_ + t)*1024 + colU);
            #pragma unroll
            for (int r = 0; r < 4; ++r)
                bv[r] = ld_u16p(belh + ((size_t)(crow0 + r)*T_ + tn)*H_ + colU);
            ISSA(srow_r);
            f32x4 acc2 = {};
            WAITV(28); SEC2(0);
            WAITV(24); SEC2(1);
            WAITV(20); SEC2(2);
            WAITV(16); SEC2(3);
            WAITV(12); SEC2(4);
            WAITV(8);  SEC2(5);
            WAITV(4);  SEC2(6);
            WAITV(0);  SEC2(7);
            #pragma unroll
            for (int r = 0; r < 4; ++r) {
                unsigned short x16 = (unsigned short)xc3v[r];
                float ns = tanhf_(acc2[r] + (float)(*(_Float16*)&x16));
                float sn = (1.f - u_reg[r])*S_reg[r] + u_reg[r]*ns;
                if (t < T_-1) {
                    unsigned short us = (unsigned short)bv[r];
                    float bel = (float)(*(_Float16*)&us);
                    float ss = bel * sn;
                    S_reg[r] = ss;
                    _Float16 hs = (_Float16)ss;
                    st_l2_u16(ssh + ((size_t)(crow0 + r) << 10) + colU,
                              (unsigned)*(unsigned short*)&hs);
                } else {
                    pout[r] = sn * woc;
                }
            }
        }
        group_barrier32(flags, gbase, j, ++it);
    }
    #undef ISSA
    #undef SEC1
    #undef SEC2
    // ---- final: sum pout over this wave's 16 cols, atomicAdd per row ----
    #pragma unroll
    for (int r = 0; r < 4; ++r) {
        float v = pout[r];
        v += __shfl_xor(v, 1, 64);
        v += __shfl_xor(v, 2, 64);
        v += __shfl_xor(v, 4, 64);
        v += __shfl_xor(v, 8, 64);
        if (ll == 0) atomicAdd(&outacc[crow0 + r], v);
    }
}

__global__ void finish_k(const float* __restrict__ acc, const float* __restrict__ bo,
                         float* __restrict__ out) {
    int i = threadIdx.x;
    out[i] = sigmoidf_(acc[i] + bo[0]);
}

extern "C" void kernel_launch(void* const* d_in, const int* in_sizes, int n_in,
                              void* d_out, int out_size, void* d_ws, size_t ws_size,
                              hipStream_t stream) {
    const float* x   = (const float*)d_in[0];
    const float* td  = (const float*)d_in[1];
    const float* Wb  = (const float*)d_in[2];
    const float* bb  = (const float*)d_in[3];
    const float* W1  = (const float*)d_in[4];
    const float* b1  = (const float*)d_in[5];
    const float* W2  = (const float*)d_in[6];
    const float* b2  = (const float*)d_in[7];
    const float* W3  = (const float*)d_in[8];
    const float* b3  = (const float*)d_in[9];
    const float* Wo  = (const float*)d_in[10];
    const float* bo  = (const float*)d_in[11];
    float* out = (float*)d_out;

    char* p = (char*)d_ws;
    auto carve = [&](size_t bytes) { char* r = p; p += (bytes + 255) & ~(size_t)255; return r; };
    int*      bar    = (int*)      carve(2048);              // 8 groups x 64 flags
    int*      claim  = (int*)      carve(256);               // 8 XCD slot counters
    float*    outacc = (float*)    carve(1024);              // 256 partial sums
    _Float16* ssh    = (_Float16*) carve((size_t)B_*H_*2);   // f16 state exchange
    _Float16* rsh    = (_Float16*) carve((size_t)B_*H_*2);   // f16 r*state exchange
    _Float16* xh     = (_Float16*) carve((size_t)NT*IN_*2);
    _Float16* tdh    = (_Float16*) carve((size_t)NT*IN_*2);
    _Float16* belh   = (_Float16*) carve((size_t)NT*H_*2);
    _Float16* Wbh    = (_Float16*) carve((size_t)H_*IN_*2);
    _Float16* wx12h  = (_Float16*) carve((size_t)2048*512*2);
    _Float16* wx3h   = (_Float16*) carve((size_t)1024*512*2);
    _Float16* xc12   = (_Float16*) carve((size_t)NT*2048*2); // 100.7 MB
    _Float16* xc3    = (_Float16*) carve((size_t)NT*1024*2); // 50.3 MB

    // zero: flags + claim + outacc + ssh (contiguous at front)
    size_t zbytes = 2048 + 256 + 1024 + (size_t)B_*H_*2;
    (void)hipMemsetAsync(bar, 0, zbytes, stream);

    const int thr = 256;
    int n8;
    n8 = NT*IN_/8;     cvt_f32_f16_k<<<(n8+thr-1)/thr, thr, 0, stream>>>(x,  xh,  n8);
    n8 = NT*IN_/8;     cvt_f32_f16_k<<<(n8+thr-1)/thr, thr, 0, stream>>>(td, tdh, n8);
    n8 = H_*IN_/8;     cvt_f32_f16_k<<<(n8+thr-1)/thr, thr, 0, stream>>>(Wb, Wbh, n8);
    n8 = H_*512/8;     pack_xpart_k<<<(n8+thr-1)/thr, thr, 0, stream>>>(W1, wx12h, n8);
    n8 = H_*512/8;     pack_xpart_k<<<(n8+thr-1)/thr, thr, 0, stream>>>(W2, wx12h + (size_t)1024*512, n8);
    n8 = H_*512/8;     pack_xpart_k<<<(n8+thr-1)/thr, thr, 0, stream>>>(W3, wx3h, n8);

    belta_gemm_k<<<(NT/64)*(H_/128), 256, 0, stream>>>(tdh, Wbh, bb, belh);
    xc_gemm_k<<<(NT/64)*(2048/128), 256, 0, stream>>>(xh, wx12h, b1, b2, xc12, 2048, 16);
    xc_gemm_k<<<(NT/64)*(1024/128), 256, 0, stream>>>(xh, wx3h,  b3, b3, xc3,  1024, 8);

    recur_k<<<256, 256, 0, stream>>>(belh, W1, W2, W3, xc12, xc3, Wo,
                                     ssh, rsh, bar, claim, outacc);
    finish_k<<<1, 256, 0, stream>>>(outacc, bo, out);
}

// Round 16
// 1454.094 us; speedup vs baseline: 1.7521x; 1.0239x over previous
//
#include <hip/hip_runtime.h>
#include <hip/hip_fp16.h>

#define B_  256
#define T_  96
#define IN_ 512
#define H_  1024
#define K1  1536          // H + IN
#define NT  (B_*T_)       // 24576

// recur_k: 8 XCD-groups x 32 blocks (runtime XCC_ID). Group owns 32 batch rows;
// block owns 32 cols. x-part precomputed (Xc12/Xc3).
// P1: fp8 state exchange (ssh) x fp8 W12s(x8) -> native fp8 MFMA (scale 0.125).
// P2: f16 r*s exchange (rsh) x f16 W3s -> f16 MFMA (r14-proven path).
#define W12S_OFF 0        // fp8: ((k8*64 + row))*8 ; 65536 B
#define W3S_OFF  65536    // f16: ((k8*32 + row))*16 ; 65536 B -> total 131072 B

typedef _Float16 f16x8 __attribute__((ext_vector_type(8)));
typedef float    f32x4 __attribute__((ext_vector_type(4)));

__device__ __forceinline__ float sigmoidf_(float z) { return 1.f/(1.f+__expf(-z)); }
__device__ __forceinline__ float tanhf_(float z)    { return 1.f - 2.f/(__expf(2.f*z)+1.f); }

// sc0 data path = bypass L1, served by this XCD's L2 (r14-proven for data)
__device__ __forceinline__ uint2 ld_l2_b64(const void* p){
    uint2 r; asm volatile("global_load_dwordx2 %0, %1, off sc0" : "=&v"(r) : "v"(p)); return r;
}
__device__ __forceinline__ uint4 ld_l2_b128(const void* p){
    uint4 r; asm volatile("global_load_dwordx4 %0, %1, off sc0" : "=&v"(r) : "v"(p)); return r;
}
__device__ __forceinline__ unsigned ld_u16p(const void* p){
    unsigned r; asm volatile("global_load_ushort %0, %1, off" : "=&v"(r) : "v"(p)); return r;
}
__device__ __forceinline__ void st_l2_u8(void* p, unsigned v){
    asm volatile("global_store_byte %0, %1, off sc0" :: "v"(p), "v"(v) : "memory");
}
__device__ __forceinline__ void st_l2_u16(void* p, unsigned v){
    asm volatile("global_store_short %0, %1, off sc0" :: "v"(p), "v"(v) : "memory");
}
#define WAITV(n) do { asm volatile("s_waitcnt vmcnt(" #n ")" ::: "memory"); \
                      __builtin_amdgcn_sched_barrier(0); } while(0)
__device__ __forceinline__ void waitv0_(){ asm volatile("s_waitcnt vmcnt(0)" ::: "memory"); }

__device__ __forceinline__ unsigned to_fp8(float x){
    return (unsigned)__builtin_amdgcn_cvt_pk_fp8_f32(x, x, 0, false) & 0xFFu;
}

// ---------------- prep: fp32 -> fp16 ----------------
__global__ void cvt_f32_f16_k(const float* __restrict__ src, _Float16* __restrict__ dst, int n8) {
    int i = blockIdx.x*blockDim.x + threadIdx.x;
    if (i >= n8) return;
    const float4* s = (const float4*)src;
    float4 a = s[2*(size_t)i], b = s[2*(size_t)i+1];
    f16x8 o;
    o[0]=(_Float16)a.x; o[1]=(_Float16)a.y; o[2]=(_Float16)a.z; o[3]=(_Float16)a.w;
    o[4]=(_Float16)b.x; o[5]=(_Float16)b.y; o[6]=(_Float16)b.z; o[7]=(_Float16)b.w;
    *(f16x8*)(dst + 8*(size_t)i) = o;
}

// pack x-part (cols 1024..1536) of a weight matrix to f16 (rows x 512)
__global__ void pack_xpart_k(const float* __restrict__ W, _Float16* __restrict__ dst, int n8) {
    int i = blockIdx.x*blockDim.x + threadIdx.x;
    if (i >= n8) return;
    int row = i >> 6, slot = i & 63;
    const float* src = W + (size_t)row*K1 + 1024 + slot*8;
    float4 a = *(const float4*)src, b = *(const float4*)(src+4);
    f16x8 o;
    o[0]=(_Float16)a.x; o[1]=(_Float16)a.y; o[2]=(_Float16)a.z; o[3]=(_Float16)a.w;
    o[4]=(_Float16)b.x; o[5]=(_Float16)b.y; o[6]=(_Float16)b.z; o[7]=(_Float16)b.w;
    *(f16x8*)(dst + (size_t)row*512 + slot*8) = o;
}

// ---------------- belta = exp(-relu(td @ Wb^T + bb)) ----------------
__global__ void __launch_bounds__(256) belta_gemm_k(const _Float16* __restrict__ td,
                                                    const _Float16* __restrict__ Wbh,
                                                    const float* __restrict__ bb,
                                                    _Float16* __restrict__ belta) {
    __shared__ _Float16 As[64][136];
    __shared__ _Float16 Bs[128][136];
    const int bid = blockIdx.x;
    const int mt = bid >> 3, nt = bid & 7;
    const int bt0 = mt*64, h0 = nt*128;
    const int tid = threadIdx.x;
    const int w = tid >> 6, l = tid & 63;
    const int wm = (w>>1)*32, wn = (w&1)*64;
    f32x4 acc[2][4] = {};
    for (int kc = 0; kc < 4; ++kc) {
        const int kbase = kc*128;
        #pragma unroll
        for (int p = 0; p < 4; ++p) {
            int unit = tid + 256*p; int r = unit>>4, cu = unit&15;
            *(uint4*)&As[r][cu*8] = *(const uint4*)(td + (size_t)(bt0+r)*IN_ + kbase + cu*8);
        }
        #pragma unroll
        for (int p = 0; p < 8; ++p) {
            int unit = tid + 256*p; int r = unit>>4, cu = unit&15;
            *(uint4*)&Bs[r][cu*8] = *(const uint4*)(Wbh + (size_t)(h0+r)*IN_ + kbase + cu*8);
        }
        __syncthreads();
        #pragma unroll
        for (int ks = 0; ks < 4; ++ks) {
            const int kk = ks*32 + (l>>4)*8;
            f16x8 a0 = *(const f16x8*)&As[wm +      (l&15)][kk];
            f16x8 a1 = *(const f16x8*)&As[wm + 16 + (l&15)][kk];
            #pragma unroll
            for (int ni = 0; ni < 4; ++ni) {
                f16x8 b = *(const f16x8*)&Bs[wn + ni*16 + (l&15)][kk];
                acc[0][ni] = __builtin_amdgcn_mfma_f32_16x16x32_f16(a0, b, acc[0][ni], 0,0,0);
                acc[1][ni] = __builtin_amdgcn_mfma_f32_16x16x32_f16(a1, b, acc[1][ni], 0,0,0);
            }
        }
        __syncthreads();
    }
    #pragma unroll
    for (int mi = 0; mi < 2; ++mi)
    #pragma unroll
    for (int ni = 0; ni < 4; ++ni)
    #pragma unroll
    for (int r = 0; r < 4; ++r) {
        int m_l = wm + mi*16 + (l>>4)*4 + r;
        int n_l = wn + ni*16 + (l&15);
        int bt = bt0 + m_l, h = h0 + n_l;
        float z = acc[mi][ni][r] + bb[h];
        belta[(size_t)bt*H_ + h] = (_Float16)__expf(-fmaxf(z, 0.f));
    }
}

// ---------------- Xc = x @ Wx^T + bias (f16 out), N = 2048 or 1024 ----------------
__global__ void __launch_bounds__(256) xc_gemm_k(const _Float16* __restrict__ A,
                                                 const _Float16* __restrict__ Bh,
                                                 const float* __restrict__ bias0,
                                                 const float* __restrict__ bias1,
                                                 _Float16* __restrict__ out,
                                                 int N, int nblk) {
    __shared__ _Float16 As[64][136];
    __shared__ _Float16 Bs[128][136];
    const int bid = blockIdx.x;
    const int mt = bid / nblk, nt = bid - mt*nblk;
    const int bt0 = mt*64, h0 = nt*128;
    const int tid = threadIdx.x;
    const int w = tid >> 6, l = tid & 63;
    const int wm = (w>>1)*32, wn = (w&1)*64;
    f32x4 acc[2][4] = {};
    for (int kc = 0; kc < 4; ++kc) {
        const int kbase = kc*128;
        #pragma unroll
        for (int p = 0; p < 4; ++p) {
            int unit = tid + 256*p; int r = unit>>4, cu = unit&15;
            *(uint4*)&As[r][cu*8] = *(const uint4*)(A + (size_t)(bt0+r)*IN_ + kbase + cu*8);
        }
        #pragma unroll
        for (int p = 0; p < 8; ++p) {
            int unit = tid + 256*p; int r = unit>>4, cu = unit&15;
            *(uint4*)&Bs[r][cu*8] = *(const uint4*)(Bh + (size_t)(h0+r)*IN_ + kbase + cu*8);
        }
        __syncthreads();
        #pragma unroll
        for (int ks = 0; ks < 4; ++ks) {
            const int kk = ks*32 + (l>>4)*8;
            f16x8 a0 = *(const f16x8*)&As[wm +      (l&15)][kk];
            f16x8 a1 = *(const f16x8*)&As[wm + 16 + (l&15)][kk];
            #pragma unroll
            for (int ni = 0; ni < 4; ++ni) {
                f16x8 b = *(const f16x8*)&Bs[wn + ni*16 + (l&15)][kk];
                acc[0][ni] = __builtin_amdgcn_mfma_f32_16x16x32_f16(a0, b, acc[0][ni], 0,0,0);
                acc[1][ni] = __builtin_amdgcn_mfma_f32_16x16x32_f16(a1, b, acc[1][ni], 0,0,0);
            }
        }
        __syncthreads();
    }
    #pragma unroll
    for (int mi = 0; mi < 2; ++mi)
    #pragma unroll
    for (int ni = 0; ni < 4; ++ni)
    #pragma unroll
    for (int r = 0; r < 4; ++r) {
        int m_l = wm + mi*16 + (l>>4)*4 + r;
        int n_l = wn + ni*16 + (l&15);
        int bt = bt0 + m_l, h = h0 + n_l;
        float z = acc[mi][ni][r] + (h < 1024 ? bias0[h] : bias1[h-1024]);
        out[(size_t)bt*N + h] = (_Float16)z;
    }
}

// ---------------- XCD-local barrier (32 blocks; r14-proven agent atomics) ----------------
__device__ __forceinline__ void group_barrier32(int* flags, int gbase, int j, int it) {
    waitv0_();                 // sc0 data stores committed to L2 before publishing
    __syncthreads();
    if (threadIdx.x == 0)
        __hip_atomic_store(&flags[gbase + j], it, __ATOMIC_RELAXED, __HIP_MEMORY_SCOPE_AGENT);
    for (;;) {
        int v = __hip_atomic_load(&flags[gbase + (threadIdx.x & 31)],
                                  __ATOMIC_RELAXED, __HIP_MEMORY_SCOPE_AGENT);
        if (__syncthreads_count(v < it) == 0) break;
        __builtin_amdgcn_s_sleep(1);
    }
}

// ---------------- recurrent scan: XCD-local, P1 native fp8, P2 f16 ----------------
__global__ void __launch_bounds__(256, 1) recur_k(
    const _Float16* __restrict__ belh,   // (B,T,H)
    const float* __restrict__ W1, const float* __restrict__ W2, const float* __restrict__ W3,
    const _Float16* __restrict__ xc12,   // (B*T, 2048): x@W12x^T + b (u|r)
    const _Float16* __restrict__ xc3,    // (B*T, 1024): x@W3x^T + b3
    const float* __restrict__ Wo,
    unsigned char* __restrict__ ssh,     // (256,1024) fp8 scaled state — L2 exchange
    _Float16* __restrict__ rsh,          // (256,1024) f16 r*state — L2 exchange
    int* flags, int* claim, float* __restrict__ outacc)
{
    __shared__ __align__(16) char smem[131072];
    __shared__ int sh_gid[2];
    const int tid = threadIdx.x;
    if (tid == 0) {
        int xcd;
        asm volatile("s_getreg_b32 %0, hwreg(HW_REG_XCC_ID)" : "=s"(xcd));
        xcd &= 7;
        sh_gid[0] = xcd;
        sh_gid[1] = atomicAdd(&claim[xcd], 1) & 31;
    }
    __syncthreads();
    const int g = sh_gid[0], j = sh_gid[1];
    const int gbase = g*64, grow0 = g*32;
    const int w = tid >> 6, l = tid & 63;
    const int lh = l >> 4, ll = l & 15;
    const int mi = w >> 1, nc = w & 1;   // wave = (M-frag, N-half)

    // ---- LDS fill: W12 state-part fp8 x8 (64 rows x 128 k8-slots, k-major) ----
    for (int u = tid; u < 64*128; u += 256) {
        int row = u >> 7, slot = u & 127;
        const float* src = (row < 32 ? W1 + (size_t)(32*j + row)*K1
                                     : W2 + (size_t)(32*j + row-32)*K1) + slot*8;
        unsigned lo = 0, hi = 0;
        lo = __builtin_amdgcn_cvt_pk_fp8_f32(src[0]*8.f, src[1]*8.f, lo, false);
        lo = __builtin_amdgcn_cvt_pk_fp8_f32(src[2]*8.f, src[3]*8.f, lo, true);
        hi = __builtin_amdgcn_cvt_pk_fp8_f32(src[4]*8.f, src[5]*8.f, hi, false);
        hi = __builtin_amdgcn_cvt_pk_fp8_f32(src[6]*8.f, src[7]*8.f, hi, true);
        uint2 o; o.x = lo; o.y = hi;
        *(uint2*)(smem + W12S_OFF + ((size_t)slot*64 + row)*8) = o;
    }
    // ---- W3 state-part f16 (32 rows x 128 k8-slots, k-major) ----
    for (int u = tid; u < 32*128; u += 256) {
        int row = u >> 7, slot = u & 127;
        const float* src = W3 + (size_t)(32*j + row)*K1 + slot*8;
        float4 f0 = *(const float4*)src, f1 = *(const float4*)(src+4);
        f16x8 h;
        h[0]=(_Float16)f0.x; h[1]=(_Float16)f0.y; h[2]=(_Float16)f0.z; h[3]=(_Float16)f0.w;
        h[4]=(_Float16)f1.x; h[5]=(_Float16)f1.y; h[6]=(_Float16)f1.z; h[7]=(_Float16)f1.w;
        *(f16x8*)(smem + W3S_OFF + ((size_t)slot*32 + row)*16) = h;
    }
    __syncthreads();

    const int colU = j*32 + nc*16 + ll;              // owned output column
    const float woc = Wo[colU];
    const int crow0 = grow0 + mi*16 + lh*4;          // epilogue rows (+r)

    // per-lane A bases: row = grow0 + mi*16 + ll, k-offset lh*8
    const unsigned char* srow_s = ssh + ((size_t)(grow0 + mi*16 + ll) << 10) + lh*8;  // fp8
    const _Float16*      srow_r = rsh + ((size_t)(grow0 + mi*16 + ll) << 10) + lh*8;  // f16

    float S_reg[4] = {0.f,0.f,0.f,0.f};
    float pout[4]  = {0.f,0.f,0.f,0.f};
    int it = 0;

    #define SEC1(S, AB) do { \
        _Pragma("unroll") for (int kf = 0; kf < 4; ++kf) { \
            const int kx = (S)*4 + kf; \
            long long a = __builtin_bit_cast(long long, AB[kx]); \
            long long bu = __builtin_bit_cast(long long, \
                *(const uint2*)(smem + W12S_OFF + (((kx*4+lh)*64) + nc*16 + ll)*8)); \
            long long br = __builtin_bit_cast(long long, \
                *(const uint2*)(smem + W12S_OFF + (((kx*4+lh)*64) + 32 + nc*16 + ll)*8)); \
            accu = __builtin_amdgcn_mfma_f32_16x16x32_fp8_fp8(a, bu, accu, 0,0,0); \
            accr = __builtin_amdgcn_mfma_f32_16x16x32_fp8_fp8(a, br, accr, 0,0,0); \
        } } while(0)
    #define SEC2(S, AB) do { \
        _Pragma("unroll") for (int kf = 0; kf < 4; ++kf) { \
            const int kx = (S)*4 + kf; \
            f16x8 a = *(const f16x8*)&AB[kx]; \
            f16x8 b = *(const f16x8*)(smem + W3S_OFF + (((kx*4+lh)*32) + nc*16 + ll)*16); \
            acc2 = __builtin_amdgcn_mfma_f32_16x16x32_f16(a, b, acc2, 0,0,0); \
        } } while(0)

    for (int t = 0; t < T_; ++t) {
        float u_reg[4];
        { // ---- P1: u,r = sigmoid(0.125*(fp8 s @ fp8 8*W12s^T) + Xc12) ----
            unsigned xcu[4], xcr[4];
            #pragma unroll
            for (int r = 0; r < 4; ++r)
                xcu[r] = ld_u16p(xc12 + ((size_t)(crow0 + r)*T_ + t)*2048 + colU);
            #pragma unroll
            for (int r = 0; r < 4; ++r)
                xcr[r] = ld_u16p(xc12 + ((size_t)(crow0 + r)*T_ + t)*2048 + 1024 + colU);
            uint2 ab1[32];                           // fp8 A frags (64 VGPR)
            #pragma unroll
            for (int k2 = 0; k2 < 32; ++k2)
                ab1[k2] = ld_l2_b64(srow_s + k2*32);
            f32x4 accu = {}, accr = {};
            WAITV(28); SEC1(0, ab1);
            WAITV(24); SEC1(1, ab1);
            WAITV(20); SEC1(2, ab1);
            WAITV(16); SEC1(3, ab1);
            WAITV(12); SEC1(4, ab1);
            WAITV(8);  SEC1(5, ab1);
            WAITV(4);  SEC1(6, ab1);
            WAITV(0);  SEC1(7, ab1);
            #pragma unroll
            for (int r = 0; r < 4; ++r) {
                unsigned short uu16 = (unsigned short)xcu[r], rr16 = (unsigned short)xcr[r];
                float uu = sigmoidf_(accu[r]*0.125f + (float)(*(_Float16*)&uu16));
                float rr = sigmoidf_(accr[r]*0.125f + (float)(*(_Float16*)&rr16));
                u_reg[r] = uu;
                _Float16 hv = (_Float16)(rr * S_reg[r]);
                st_l2_u16(rsh + ((size_t)(crow0 + r) << 10) + colU,
                          (unsigned)*(unsigned short*)&hv);
            }
        }
        group_barrier32(flags, gbase, j, ++it);
        { // ---- P2: ns = tanh((f16 r*s @ f16 W3s^T) + Xc3); state update ----
            const int tn = (t < T_-1) ? t+1 : t;
            unsigned xc3v[4], bv[4];
            #pragma unroll
            for (int r = 0; r < 4; ++r)
                xc3v[r] = ld_u16p(xc3 + ((size_t)(crow0 + r)*T_ + t)*1024 + colU);
            #pragma unroll
            for (int r = 0; r < 4; ++r)
                bv[r] = ld_u16p(belh + ((size_t)(crow0 + r)*T_ + tn)*H_ + colU);
            uint4 ab2[32];                           // f16 A frags (128 VGPR)
            #pragma unroll
            for (int k2 = 0; k2 < 32; ++k2)
                ab2[k2] = ld_l2_b128(srow_r + k2*32);
            f32x4 acc2 = {};
            WAITV(28); SEC2(0, ab2);
            WAITV(24); SEC2(1, ab2);
            WAITV(20); SEC2(2, ab2);
            WAITV(16); SEC2(3, ab2);
            WAITV(12); SEC2(4, ab2);
            WAITV(8);  SEC2(5, ab2);
            WAITV(4);  SEC2(6, ab2);
            WAITV(0);  SEC2(7, ab2);
            #pragma unroll
            for (int r = 0; r < 4; ++r) {
                unsigned short x16 = (unsigned short)xc3v[r];
                float ns = tanhf_(acc2[r] + (float)(*(_Float16*)&x16));
                float sn = (1.f - u_reg[r])*S_reg[r] + u_reg[r]*ns;
                if (t < T_-1) {
                    unsigned short us = (unsigned short)bv[r];
                    float bel = (float)(*(_Float16*)&us);
                    float ss = bel * sn;
                    S_reg[r] = ss;
                    st_l2_u8(ssh + ((size_t)(crow0 + r) << 10) + colU, to_fp8(ss));
                } else {
                    pout[r] = sn * woc;
                }
            }
        }
        group_barrier32(flags, gbase, j, ++it);
    }
    #undef SEC1
    #undef SEC2
    // ---- final: sum pout over this wave's 16 cols, atomicAdd per row ----
    #pragma unroll
    for (int r = 0; r < 4; ++r) {
        float v = pout[r];
        v += __shfl_xor(v, 1, 64);
        v += __shfl_xor(v, 2, 64);
        v += __shfl_xor(v, 4, 64);
        v += __shfl_xor(v, 8, 64);
        if (ll == 0) atomicAdd(&outacc[crow0 + r], v);
    }
}

__global__ void finish_k(const float* __restrict__ acc, const float* __restrict__ bo,
                         float* __restrict__ out) {
    int i = threadIdx.x;
    out[i] = sigmoidf_(acc[i] + bo[0]);
}

extern "C" void kernel_launch(void* const* d_in, const int* in_sizes, int n_in,
                              void* d_out, int out_size, void* d_ws, size_t ws_size,
                              hipStream_t stream) {
    const float* x   = (const float*)d_in[0];
    const float* td  = (const float*)d_in[1];
    const float* Wb  = (const float*)d_in[2];
    const float* bb  = (const float*)d_in[3];
    const float* W1  = (const float*)d_in[4];
    const float* b1  = (const float*)d_in[5];
    const float* W2  = (const float*)d_in[6];
    const float* b2  = (const float*)d_in[7];
    const float* W3  = (const float*)d_in[8];
    const float* b3  = (const float*)d_in[9];
    const float* Wo  = (const float*)d_in[10];
    const float* bo  = (const float*)d_in[11];
    float* out = (float*)d_out;

    char* p = (char*)d_ws;
    auto carve = [&](size_t bytes) { char* r = p; p += (bytes + 255) & ~(size_t)255; return r; };
    int*           bar    = (int*)           carve(2048);              // 8 groups x 64 flags
    int*           claim  = (int*)           carve(256);               // 8 XCD slot counters
    float*         outacc = (float*)         carve(1024);              // 256 partial sums
    unsigned char* ssh    = (unsigned char*) carve((size_t)B_*H_);     // fp8 state exchange
    _Float16*      rsh    = (_Float16*)      carve((size_t)B_*H_*2);   // f16 r*state exchange
    _Float16*      xh     = (_Float16*)      carve((size_t)NT*IN_*2);
    _Float16*      tdh    = (_Float16*)      carve((size_t)NT*IN_*2);
    _Float16*      belh   = (_Float16*)      carve((size_t)NT*H_*2);
    _Float16*      Wbh    = (_Float16*)      carve((size_t)H_*IN_*2);
    _Float16*      wx12h  = (_Float16*)      carve((size_t)2048*512*2);
    _Float16*      wx3h   = (_Float16*)      carve((size_t)1024*512*2);
    _Float16*      xc12   = (_Float16*)      carve((size_t)NT*2048*2); // 100.7 MB
    _Float16*      xc3    = (_Float16*)      carve((size_t)NT*1024*2); // 50.3 MB

    // zero: flags + claim + outacc + ssh (contiguous at front)
    size_t zbytes = 2048 + 256 + 1024 + (size_t)B_*H_;
    (void)hipMemsetAsync(bar, 0, zbytes, stream);

    const int thr = 256;
    int n8;
    n8 = NT*IN_/8;     cvt_f32_f16_k<<<(n8+thr-1)/thr, thr, 0, stream>>>(x,  xh,  n8);
    n8 = NT*IN_/8;     cvt_f32_f16_k<<<(n8+thr-1)/thr, thr, 0, stream>>>(td, tdh, n8);
    n8 = H_*IN_/8;     cvt_f32_f16_k<<<(n8+thr-1)/thr, thr, 0, stream>>>(Wb, Wbh, n8);
    n8 = H_*512/8;     pack_xpart_k<<<(n8+thr-1)/thr, thr, 0, stream>>>(W1, wx12h, n8);
    n8 = H_*512/8;     pack_xpart_k<<<(n8+thr-1)/thr, thr, 0, stream>>>(W2, wx12h + (size_t)1024*512, n8);
    n8 = H_*512/8;     pack_xpart_k<<<(n8+thr-1)/thr, thr, 0, stream>>>(W3, wx3h, n8);

    belta_gemm_k<<<(NT/64)*(H_/128), 256, 0, stream>>>(tdh, Wbh, bb, belh);
    xc_gemm_k<<<(NT/64)*(2048/128), 256, 0, stream>>>(xh, wx12h, b1, b2, xc12, 2048, 16);
    xc_gemm_k<<<(NT/64)*(1024/128), 256, 0, stream>>>(xh, wx3h,  b3, b3, xc3,  1024, 8);

    recur_k<<<256, 256, 0, stream>>>(belh, W1, W2, W3, xc12, xc3, Wo,
                                     ssh, rsh, bar, claim, outacc);
    finish_k<<<1, 256, 0, stream>>>(outacc, bo, out);
}

// Round 17
// 1395.393 us; speedup vs baseline: 1.8258x; 1.0421x over previous
//
#include <hip/hip_runtime.h>
#include <hip/hip_fp16.h>

#define B_  256
#define T_  96
#define IN_ 512
#define H_  1024
#define K1  1536          // H + IN
#define NT  (B_*T_)       // 24576

// recur_k: 8 XCD-groups x 32 blocks (runtime XCC_ID). Group owns 32 batch rows;
// block owns 32 cols. x-part precomputed (Xc12/Xc3).
// P1: fp8 state exchange (ssh) x fp8 W12s(x8) -> native fp8 MFMA (scale 0.125).
// P2: f16 r*s exchange (rsh) x f16 W3s -> f16 MFMA.
// NEW (r17): xc/bel scalar streams are prefetched one phase ahead (youngest in
// vmcnt FIFO), so phase start waits only on L2 exchange loads.
#define W12S_OFF 0        // fp8: ((k8*64 + row))*8 ; 65536 B
#define W3S_OFF  65536    // f16: ((k8*32 + row))*16 ; 65536 B -> total 131072 B

typedef _Float16 f16x8 __attribute__((ext_vector_type(8)));
typedef float    f32x4 __attribute__((ext_vector_type(4)));

__device__ __forceinline__ float sigmoidf_(float z) { return 1.f/(1.f+__expf(-z)); }
__device__ __forceinline__ float tanhf_(float z)    { return 1.f - 2.f/(__expf(2.f*z)+1.f); }

// sc0 data path = bypass L1, served by this XCD's L2 (r14-proven for data)
__device__ __forceinline__ uint2 ld_l2_b64(const void* p){
    uint2 r; asm volatile("global_load_dwordx2 %0, %1, off sc0" : "=&v"(r) : "v"(p)); return r;
}
__device__ __forceinline__ uint4 ld_l2_b128(const void* p){
    uint4 r; asm volatile("global_load_dwordx4 %0, %1, off sc0" : "=&v"(r) : "v"(p)); return r;
}
__device__ __forceinline__ unsigned ld_u16p(const void* p){
    unsigned r; asm volatile("global_load_ushort %0, %1, off" : "=&v"(r) : "v"(p)); return r;
}
__device__ __forceinline__ void st_l2_u8(void* p, unsigned v){
    asm volatile("global_store_byte %0, %1, off sc0" :: "v"(p), "v"(v) : "memory");
}
__device__ __forceinline__ void st_l2_u16(void* p, unsigned v){
    asm volatile("global_store_short %0, %1, off sc0" :: "v"(p), "v"(v) : "memory");
}
#define WAITV(n) do { asm volatile("s_waitcnt vmcnt(" #n ")" ::: "memory"); \
                      __builtin_amdgcn_sched_barrier(0); } while(0)
__device__ __forceinline__ void waitv0_(){ asm volatile("s_waitcnt vmcnt(0)" ::: "memory"); }

__device__ __forceinline__ unsigned to_fp8(float x){
    return (unsigned)__builtin_amdgcn_cvt_pk_fp8_f32(x, x, 0, false) & 0xFFu;
}

// ---------------- prep: fp32 -> fp16 ----------------
__global__ void cvt_f32_f16_k(const float* __restrict__ src, _Float16* __restrict__ dst, int n8) {
    int i = blockIdx.x*blockDim.x + threadIdx.x;
    if (i >= n8) return;
    const float4* s = (const float4*)src;
    float4 a = s[2*(size_t)i], b = s[2*(size_t)i+1];
    f16x8 o;
    o[0]=(_Float16)a.x; o[1]=(_Float16)a.y; o[2]=(_Float16)a.z; o[3]=(_Float16)a.w;
    o[4]=(_Float16)b.x; o[5]=(_Float16)b.y; o[6]=(_Float16)b.z; o[7]=(_Float16)b.w;
    *(f16x8*)(dst + 8*(size_t)i) = o;
}

// pack x-part (cols 1024..1536) of a weight matrix to f16 (rows x 512)
__global__ void pack_xpart_k(const float* __restrict__ W, _Float16* __restrict__ dst, int n8) {
    int i = blockIdx.x*blockDim.x + threadIdx.x;
    if (i >= n8) return;
    int row = i >> 6, slot = i & 63;
    const float* src = W + (size_t)row*K1 + 1024 + slot*8;
    float4 a = *(const float4*)src, b = *(const float4*)(src+4);
    f16x8 o;
    o[0]=(_Float16)a.x; o[1]=(_Float16)a.y; o[2]=(_Float16)a.z; o[3]=(_Float16)a.w;
    o[4]=(_Float16)b.x; o[5]=(_Float16)b.y; o[6]=(_Float16)b.z; o[7]=(_Float16)b.w;
    *(f16x8*)(dst + (size_t)row*512 + slot*8) = o;
}

// ---------------- belta = exp(-relu(td @ Wb^T + bb)) ----------------
__global__ void __launch_bounds__(256) belta_gemm_k(const _Float16* __restrict__ td,
                                                    const _Float16* __restrict__ Wbh,
                                                    const float* __restrict__ bb,
                                                    _Float16* __restrict__ belta) {
    __shared__ _Float16 As[64][136];
    __shared__ _Float16 Bs[128][136];
    const int bid = blockIdx.x;
    const int mt = bid >> 3, nt = bid & 7;
    const int bt0 = mt*64, h0 = nt*128;
    const int tid = threadIdx.x;
    const int w = tid >> 6, l = tid & 63;
    const int wm = (w>>1)*32, wn = (w&1)*64;
    f32x4 acc[2][4] = {};
    for (int kc = 0; kc < 4; ++kc) {
        const int kbase = kc*128;
        #pragma unroll
        for (int p = 0; p < 4; ++p) {
            int unit = tid + 256*p; int r = unit>>4, cu = unit&15;
            *(uint4*)&As[r][cu*8] = *(const uint4*)(td + (size_t)(bt0+r)*IN_ + kbase + cu*8);
        }
        #pragma unroll
        for (int p = 0; p < 8; ++p) {
            int unit = tid + 256*p; int r = unit>>4, cu = unit&15;
            *(uint4*)&Bs[r][cu*8] = *(const uint4*)(Wbh + (size_t)(h0+r)*IN_ + kbase + cu*8);
        }
        __syncthreads();
        #pragma unroll
        for (int ks = 0; ks < 4; ++ks) {
            const int kk = ks*32 + (l>>4)*8;
            f16x8 a0 = *(const f16x8*)&As[wm +      (l&15)][kk];
            f16x8 a1 = *(const f16x8*)&As[wm + 16 + (l&15)][kk];
            #pragma unroll
            for (int ni = 0; ni < 4; ++ni) {
                f16x8 b = *(const f16x8*)&Bs[wn + ni*16 + (l&15)][kk];
                acc[0][ni] = __builtin_amdgcn_mfma_f32_16x16x32_f16(a0, b, acc[0][ni], 0,0,0);
                acc[1][ni] = __builtin_amdgcn_mfma_f32_16x16x32_f16(a1, b, acc[1][ni], 0,0,0);
            }
        }
        __syncthreads();
    }
    #pragma unroll
    for (int mi = 0; mi < 2; ++mi)
    #pragma unroll
    for (int ni = 0; ni < 4; ++ni)
    #pragma unroll
    for (int r = 0; r < 4; ++r) {
        int m_l = wm + mi*16 + (l>>4)*4 + r;
        int n_l = wn + ni*16 + (l&15);
        int bt = bt0 + m_l, h = h0 + n_l;
        float z = acc[mi][ni][r] + bb[h];
        belta[(size_t)bt*H_ + h] = (_Float16)__expf(-fmaxf(z, 0.f));
    }
}

// ---------------- Xc = x @ Wx^T + bias (f16 out), N = 2048 or 1024 ----------------
__global__ void __launch_bounds__(256) xc_gemm_k(const _Float16* __restrict__ A,
                                                 const _Float16* __restrict__ Bh,
                                                 const float* __restrict__ bias0,
                                                 const float* __restrict__ bias1,
                                                 _Float16* __restrict__ out,
                                                 int N, int nblk) {
    __shared__ _Float16 As[64][136];
    __shared__ _Float16 Bs[128][136];
    const int bid = blockIdx.x;
    const int mt = bid / nblk, nt = bid - mt*nblk;
    const int bt0 = mt*64, h0 = nt*128;
    const int tid = threadIdx.x;
    const int w = tid >> 6, l = tid & 63;
    const int wm = (w>>1)*32, wn = (w&1)*64;
    f32x4 acc[2][4] = {};
    for (int kc = 0; kc < 4; ++kc) {
        const int kbase = kc*128;
        #pragma unroll
        for (int p = 0; p < 4; ++p) {
            int unit = tid + 256*p; int r = unit>>4, cu = unit&15;
            *(uint4*)&As[r][cu*8] = *(const uint4*)(A + (size_t)(bt0+r)*IN_ + kbase + cu*8);
        }
        #pragma unroll
        for (int p = 0; p < 8; ++p) {
            int unit = tid + 256*p; int r = unit>>4, cu = unit&15;
            *(uint4*)&Bs[r][cu*8] = *(const uint4*)(Bh + (size_t)(h0+r)*IN_ + kbase + cu*8);
        }
        __syncthreads();
        #pragma unroll
        for (int ks = 0; ks < 4; ++ks) {
            const int kk = ks*32 + (l>>4)*8;
            f16x8 a0 = *(const f16x8*)&As[wm +      (l&15)][kk];
            f16x8 a1 = *(const f16x8*)&As[wm + 16 + (l&15)][kk];
            #pragma unroll
            for (int ni = 0; ni < 4; ++ni) {
                f16x8 b = *(const f16x8*)&Bs[wn + ni*16 + (l&15)][kk];
                acc[0][ni] = __builtin_amdgcn_mfma_f32_16x16x32_f16(a0, b, acc[0][ni], 0,0,0);
                acc[1][ni] = __builtin_amdgcn_mfma_f32_16x16x32_f16(a1, b, acc[1][ni], 0,0,0);
            }
        }
        __syncthreads();
    }
    #pragma unroll
    for (int mi = 0; mi < 2; ++mi)
    #pragma unroll
    for (int ni = 0; ni < 4; ++ni)
    #pragma unroll
    for (int r = 0; r < 4; ++r) {
        int m_l = wm + mi*16 + (l>>4)*4 + r;
        int n_l = wn + ni*16 + (l&15);
        int bt = bt0 + m_l, h = h0 + n_l;
        float z = acc[mi][ni][r] + (h < 1024 ? bias0[h] : bias1[h-1024]);
        out[(size_t)bt*N + h] = (_Float16)z;
    }
}

// ---------------- XCD-local barrier (32 blocks; proven agent atomics) ----------------
__device__ __forceinline__ void group_barrier32(int* flags, int gbase, int j, int it) {
    waitv0_();                 // drains data stores AND in-flight prefetch loads
    __syncthreads();
    if (threadIdx.x == 0)
        __hip_atomic_store(&flags[gbase + j], it, __ATOMIC_RELAXED, __HIP_MEMORY_SCOPE_AGENT);
    for (;;) {
        int v = __hip_atomic_load(&flags[gbase + (threadIdx.x & 31)],
                                  __ATOMIC_RELAXED, __HIP_MEMORY_SCOPE_AGENT);
        if (__syncthreads_count(v < it) == 0) break;
        __builtin_amdgcn_s_sleep(1);
    }
    __builtin_amdgcn_sched_barrier(0);   // keep prefetch-register uses after the drain
}

// ---------------- recurrent scan: XCD-local, P1 fp8 / P2 f16, prefetched scalars ----------------
__global__ void __launch_bounds__(256, 1) recur_k(
    const _Float16* __restrict__ belh,   // (B,T,H)
    const float* __restrict__ W1, const float* __restrict__ W2, const float* __restrict__ W3,
    const _Float16* __restrict__ xc12,   // (B*T, 2048): x@W12x^T + b (u|r)
    const _Float16* __restrict__ xc3,    // (B*T, 1024): x@W3x^T + b3
    const float* __restrict__ Wo,
    unsigned char* __restrict__ ssh,     // (256,1024) fp8 scaled state — L2 exchange
    _Float16* __restrict__ rsh,          // (256,1024) f16 r*state — L2 exchange
    int* flags, int* claim, float* __restrict__ outacc)
{
    __shared__ __align__(16) char smem[131072];
    __shared__ int sh_gid[2];
    const int tid = threadIdx.x;
    if (tid == 0) {
        int xcd;
        asm volatile("s_getreg_b32 %0, hwreg(HW_REG_XCC_ID)" : "=s"(xcd));
        xcd &= 7;
        sh_gid[0] = xcd;
        sh_gid[1] = atomicAdd(&claim[xcd], 1) & 31;
    }
    __syncthreads();
    const int g = sh_gid[0], j = sh_gid[1];
    const int gbase = g*64, grow0 = g*32;
    const int w = tid >> 6, l = tid & 63;
    const int lh = l >> 4, ll = l & 15;
    const int mi = w >> 1, nc = w & 1;   // wave = (M-frag, N-half)

    // ---- LDS fill: W12 state-part fp8 x8 (64 rows x 128 k8-slots, k-major) ----
    for (int u = tid; u < 64*128; u += 256) {
        int row = u >> 7, slot = u & 127;
        const float* src = (row < 32 ? W1 + (size_t)(32*j + row)*K1
                                     : W2 + (size_t)(32*j + row-32)*K1) + slot*8;
        unsigned lo = 0, hi = 0;
        lo = __builtin_amdgcn_cvt_pk_fp8_f32(src[0]*8.f, src[1]*8.f, lo, false);
        lo = __builtin_amdgcn_cvt_pk_fp8_f32(src[2]*8.f, src[3]*8.f, lo, true);
        hi = __builtin_amdgcn_cvt_pk_fp8_f32(src[4]*8.f, src[5]*8.f, hi, false);
        hi = __builtin_amdgcn_cvt_pk_fp8_f32(src[6]*8.f, src[7]*8.f, hi, true);
        uint2 o; o.x = lo; o.y = hi;
        *(uint2*)(smem + W12S_OFF + ((size_t)slot*64 + row)*8) = o;
    }
    // ---- W3 state-part f16 (32 rows x 128 k8-slots, k-major) ----
    for (int u = tid; u < 32*128; u += 256) {
        int row = u >> 7, slot = u & 127;
        const float* src = W3 + (size_t)(32*j + row)*K1 + slot*8;
        float4 f0 = *(const float4*)src, f1 = *(const float4*)(src+4);
        f16x8 h;
        h[0]=(_Float16)f0.x; h[1]=(_Float16)f0.y; h[2]=(_Float16)f0.z; h[3]=(_Float16)f0.w;
        h[4]=(_Float16)f1.x; h[5]=(_Float16)f1.y; h[6]=(_Float16)f1.z; h[7]=(_Float16)f1.w;
        *(f16x8*)(smem + W3S_OFF + ((size_t)slot*32 + row)*16) = h;
    }
    __syncthreads();

    const int colU = j*32 + nc*16 + ll;              // owned output column
    const float woc = Wo[colU];
    const int crow0 = grow0 + mi*16 + lh*4;          // epilogue rows (+r)

    // per-lane A bases: row = grow0 + mi*16 + ll, k-offset lh*8
    const unsigned char* srow_s = ssh + ((size_t)(grow0 + mi*16 + ll) << 10) + lh*8;  // fp8
    const _Float16*      srow_r = rsh + ((size_t)(grow0 + mi*16 + ll) << 10) + lh*8;  // f16

    float S_reg[4] = {0.f,0.f,0.f,0.f};
    float pout[4]  = {0.f,0.f,0.f,0.f};
    int it = 0;

    #define SEC1(S, AB) do { \
        _Pragma("unroll") for (int kf = 0; kf < 4; ++kf) { \
            const int kx = (S)*4 + kf; \
            long long a = __builtin_bit_cast(long long, AB[kx]); \
            long long bu = __builtin_bit_cast(long long, \
                *(const uint2*)(smem + W12S_OFF + (((kx*4+lh)*64) + nc*16 + ll)*8)); \
            long long br = __builtin_bit_cast(long long, \
                *(const uint2*)(smem + W12S_OFF + (((kx*4+lh)*64) + 32 + nc*16 + ll)*8)); \
            accu = __builtin_amdgcn_mfma_f32_16x16x32_fp8_fp8(a, bu, accu, 0,0,0); \
            accr = __builtin_amdgcn_mfma_f32_16x16x32_fp8_fp8(a, br, accr, 0,0,0); \
        } } while(0)
    #define SEC2(S, AB) do { \
        _Pragma("unroll") for (int kf = 0; kf < 4; ++kf) { \
            const int kx = (S)*4 + kf; \
            f16x8 a = *(const f16x8*)&AB[kx]; \
            f16x8 b = *(const f16x8*)(smem + W3S_OFF + (((kx*4+lh)*32) + nc*16 + ll)*16); \
            acc2 = __builtin_amdgcn_mfma_f32_16x16x32_f16(a, b, acc2, 0,0,0); \
        } } while(0)

    // ---- prologue prefetch: xcu/xcr for t=0 ----
    unsigned xcu[4], xcr[4];
    #pragma unroll
    for (int r = 0; r < 4; ++r)
        xcu[r] = ld_u16p(xc12 + ((size_t)(crow0 + r)*T_)*2048 + colU);
    #pragma unroll
    for (int r = 0; r < 4; ++r)
        xcr[r] = ld_u16p(xc12 + ((size_t)(crow0 + r)*T_)*2048 + 1024 + colU);
    waitv0_();

    for (int t = 0; t < T_; ++t) {
        const int tn = (t < T_-1) ? t+1 : t;
        float u_reg[4];
        unsigned xc3v[4], bv[4];
        { // ---- P1: u,r = sigmoid(0.125*(fp8 s @ fp8 8*W12s^T) + Xc12) ----
            uint2 ab1[32];                           // fp8 A frags (64 VGPR)
            #pragma unroll
            for (int k2 = 0; k2 < 32; ++k2)
                ab1[k2] = ld_l2_b64(srow_s + k2*32);
            // prefetch (youngest in FIFO): xc3/bel for this step's P2
            #pragma unroll
            for (int r = 0; r < 4; ++r)
                xc3v[r] = ld_u16p(xc3 + ((size_t)(crow0 + r)*T_ + t)*1024 + colU);
            #pragma unroll
            for (int r = 0; r < 4; ++r)
                bv[r] = ld_u16p(belh + ((size_t)(crow0 + r)*T_ + tn)*H_ + colU);
            f32x4 accu = {}, accr = {};
            WAITV(36); SEC1(0, ab1);
            WAITV(32); SEC1(1, ab1);
            WAITV(28); SEC1(2, ab1);
            WAITV(24); SEC1(3, ab1);
            WAITV(20); SEC1(4, ab1);
            WAITV(16); SEC1(5, ab1);
            WAITV(12); SEC1(6, ab1);
            WAITV(8);  SEC1(7, ab1);
            #pragma unroll
            for (int r = 0; r < 4; ++r) {            // uses xcu/xcr from prev phase
                unsigned short uu16 = (unsigned short)xcu[r], rr16 = (unsigned short)xcr[r];
                float uu = sigmoidf_(accu[r]*0.125f + (float)(*(_Float16*)&uu16));
                float rr = sigmoidf_(accr[r]*0.125f + (float)(*(_Float16*)&rr16));
                u_reg[r] = uu;
                _Float16 hv = (_Float16)(rr * S_reg[r]);
                st_l2_u16(rsh + ((size_t)(crow0 + r) << 10) + colU,
                          (unsigned)*(unsigned short*)&hv);
            }
        }
        group_barrier32(flags, gbase, j, ++it);      // drains prefetch into regs
        { // ---- P2: ns = tanh((f16 r*s @ f16 W3s^T) + Xc3); state update ----
            uint4 ab2[32];                           // f16 A frags (128 VGPR)
            #pragma unroll
            for (int k2 = 0; k2 < 32; ++k2)
                ab2[k2] = ld_l2_b128(srow_r + k2*32);
            // prefetch (youngest): xc12 for next step's P1
            #pragma unroll
            for (int r = 0; r < 4; ++r)
                xcu[r] = ld_u16p(xc12 + ((size_t)(crow0 + r)*T_ + tn)*2048 + colU);
            #pragma unroll
            for (int r = 0; r < 4; ++r)
                xcr[r] = ld_u16p(xc12 + ((size_t)(crow0 + r)*T_ + tn)*2048 + 1024 + colU);
            f32x4 acc2 = {};
            WAITV(36); SEC2(0, ab2);
            WAITV(32); SEC2(1, ab2);
            WAITV(28); SEC2(2, ab2);
            WAITV(24); SEC2(3, ab2);
            WAITV(20); SEC2(4, ab2);
            WAITV(16); SEC2(5, ab2);
            WAITV(12); SEC2(6, ab2);
            WAITV(8);  SEC2(7, ab2);
            #pragma unroll
            for (int r = 0; r < 4; ++r) {            // uses xc3v/bv from P1 prefetch
                unsigned short x16 = (unsigned short)xc3v[r];
                float ns = tanhf_(acc2[r] + (float)(*(_Float16*)&x16));
                float sn = (1.f - u_reg[r])*S_reg[r] + u_reg[r]*ns;
                if (t < T_-1) {
                    unsigned short us = (unsigned short)bv[r];
                    float bel = (float)(*(_Float16*)&us);
                    float ss = bel * sn;
                    S_reg[r] = ss;
                    st_l2_u8(ssh + ((size_t)(crow0 + r) << 10) + colU, to_fp8(ss));
                } else {
                    pout[r] = sn * woc;
                }
            }
        }
        group_barrier32(flags, gbase, j, ++it);
    }
    #undef SEC1
    #undef SEC2
    // ---- final: sum pout over this wave's 16 cols, atomicAdd per row ----
    #pragma unroll
    for (int r = 0; r < 4; ++r) {
        float v = pout[r];
        v += __shfl_xor(v, 1, 64);
        v += __shfl_xor(v, 2, 64);
        v += __shfl_xor(v, 4, 64);
        v += __shfl_xor(v, 8, 64);
        if (ll == 0) atomicAdd(&outacc[crow0 + r], v);
    }
}

__global__ void finish_k(const float* __restrict__ acc, const float* __restrict__ bo,
                         float* __restrict__ out) {
    int i = threadIdx.x;
    out[i] = sigmoidf_(acc[i] + bo[0]);
}

extern "C" void kernel_launch(void* const* d_in, const int* in_sizes, int n_in,
                              void* d_out, int out_size, void* d_ws, size_t ws_size,
                              hipStream_t stream) {
    const float* x   = (const float*)d_in[0];
    const float* td  = (const float*)d_in[1];
    const float* Wb  = (const float*)d_in[2];
    const float* bb  = (const float*)d_in[3];
    const float* W1  = (const float*)d_in[4];
    const float* b1  = (const float*)d_in[5];
    const float* W2  = (const float*)d_in[6];
    const float* b2  = (const float*)d_in[7];
    const float* W3  = (const float*)d_in[8];
    const float* b3  = (const float*)d_in[9];
    const float* Wo  = (const float*)d_in[10];
    const float* bo  = (const float*)d_in[11];
    float* out = (float*)d_out;

    char* p = (char*)d_ws;
    auto carve = [&](size_t bytes) { char* r = p; p += (bytes + 255) & ~(size_t)255; return r; };
    int*           bar    = (int*)           carve(2048);              // 8 groups x 64 flags
    int*           claim  = (int*)           carve(256);               // 8 XCD slot counters
    float*         outacc = (float*)         carve(1024);              // 256 partial sums
    unsigned char* ssh    = (unsigned char*) carve((size_t)B_*H_);     // fp8 state exchange
    _Float16*      rsh    = (_Float16*)      carve((size_t)B_*H_*2);   // f16 r*state exchange
    _Float16*      xh     = (_Float16*)      carve((size_t)NT*IN_*2);
    _Float16*      tdh    = (_Float16*)      carve((size_t)NT*IN_*2);
    _Float16*      belh   = (_Float16*)      carve((size_t)NT*H_*2);
    _Float16*      Wbh    = (_Float16*)      carve((size_t)H_*IN_*2);
    _Float16*      wx12h  = (_Float16*)      carve((size_t)2048*512*2);
    _Float16*      wx3h   = (_Float16*)      carve((size_t)1024*512*2);
    _Float16*      xc12   = (_Float16*)      carve((size_t)NT*2048*2); // 100.7 MB
    _Float16*      xc3    = (_Float16*)      carve((size_t)NT*1024*2); // 50.3 MB

    // zero: flags + claim + outacc + ssh (contiguous at front)
    size_t zbytes = 2048 + 256 + 1024 + (size_t)B_*H_;
    (void)hipMemsetAsync(bar, 0, zbytes, stream);

    const int thr = 256;
    int n8;
    n8 = NT*IN_/8;     cvt_f32_f16_k<<<(n8+thr-1)/thr, thr, 0, stream>>>(x,  xh,  n8);
    n8 = NT*IN_/8;     cvt_f32_f16_k<<<(n8+thr-1)/thr, thr, 0, stream>>>(td, tdh, n8);
    n8 = H_*IN_/8;     cvt_f32_f16_k<<<(n8+thr-1)/thr, thr, 0, stream>>>(Wb, Wbh, n8);
    n8 = H_*512/8;     pack_xpart_k<<<(n8+thr-1)/thr, thr, 0, stream>>>(W1, wx12h, n8);
    n8 = H_*512/8;     pack_xpart_k<<<(n8+thr-1)/thr, thr, 0, stream>>>(W2, wx12h + (size_t)1024*512, n8);
    n8 = H_*512/8;     pack_xpart_k<<<(n8+thr-1)/thr, thr, 0, stream>>>(W3, wx3h, n8);

    belta_gemm_k<<<(NT/64)*(H_/128), 256, 0, stream>>>(tdh, Wbh, bb, belh);
    xc_gemm_k<<<(NT/64)*(2048/128), 256, 0, stream>>>(xh, wx12h, b1, b2, xc12, 2048, 16);
    xc_gemm_k<<<(NT/64)*(1024/128), 256, 0, stream>>>(xh, wx3h,  b3, b3, xc3,  1024, 8);

    recur_k<<<256, 256, 0, stream>>>(belh, W1, W2, W3, xc12, xc3, Wo,
                                     ssh, rsh, bar, claim, outacc);
    finish_k<<<1, 256, 0, stream>>>(outacc, bo, out);
}

// Round 18
// 1355.095 us; speedup vs baseline: 1.8801x; 1.0297x over previous
//
#include <hip/hip_runtime.h>
#include <hip/hip_fp16.h>

#define B_  256
#define T_  96
#define IN_ 512
#define H_  1024
#define K1  1536          // H + IN
#define NT  (B_*T_)       // 24576

// recur_k: 8 XCD-groups x 32 blocks (runtime XCC_ID). Group owns 32 batch rows;
// block owns 32 cols. x-part precomputed (Xc12/Xc3).
// P1: fp8 state exchange (ssh) x fp8 W12s(x8) -> native fp8 MFMA (scale 0.125).
// P2: f16 r*s exchange (rsh) x f16 W3s -> f16 MFMA.
// r17: xc/bel scalar streams prefetched one phase ahead.
// r18: flags padded to one 128-B line each (kill false-sharing serialization).
#define W12S_OFF 0        // fp8: ((k8*64 + row))*8 ; 65536 B
#define W3S_OFF  65536    // f16: ((k8*32 + row))*16 ; 65536 B -> total 131072 B

typedef _Float16 f16x8 __attribute__((ext_vector_type(8)));
typedef float    f32x4 __attribute__((ext_vector_type(4)));

__device__ __forceinline__ float sigmoidf_(float z) { return 1.f/(1.f+__expf(-z)); }
__device__ __forceinline__ float tanhf_(float z)    { return 1.f - 2.f/(__expf(2.f*z)+1.f); }

// sc0 data path = bypass L1, served by this XCD's L2 (r14-proven for data)
__device__ __forceinline__ uint2 ld_l2_b64(const void* p){
    uint2 r; asm volatile("global_load_dwordx2 %0, %1, off sc0" : "=&v"(r) : "v"(p)); return r;
}
__device__ __forceinline__ uint4 ld_l2_b128(const void* p){
    uint4 r; asm volatile("global_load_dwordx4 %0, %1, off sc0" : "=&v"(r) : "v"(p)); return r;
}
__device__ __forceinline__ unsigned ld_u16p(const void* p){
    unsigned r; asm volatile("global_load_ushort %0, %1, off" : "=&v"(r) : "v"(p)); return r;
}
__device__ __forceinline__ void st_l2_u8(void* p, unsigned v){
    asm volatile("global_store_byte %0, %1, off sc0" :: "v"(p), "v"(v) : "memory");
}
__device__ __forceinline__ void st_l2_u16(void* p, unsigned v){
    asm volatile("global_store_short %0, %1, off sc0" :: "v"(p), "v"(v) : "memory");
}
#define WAITV(n) do { asm volatile("s_waitcnt vmcnt(" #n ")" ::: "memory"); \
                      __builtin_amdgcn_sched_barrier(0); } while(0)
__device__ __forceinline__ void waitv0_(){ asm volatile("s_waitcnt vmcnt(0)" ::: "memory"); }

__device__ __forceinline__ unsigned to_fp8(float x){
    return (unsigned)__builtin_amdgcn_cvt_pk_fp8_f32(x, x, 0, false) & 0xFFu;
}

// ---------------- fused prep: all f32->f16 conversions in one kernel ----------------
__global__ void __launch_bounds__(256) prep_cvt_k(
    const float* __restrict__ x, const float* __restrict__ td, const float* __restrict__ Wb,
    const float* __restrict__ W1, const float* __restrict__ W2, const float* __restrict__ W3,
    _Float16* __restrict__ xh, _Float16* __restrict__ tdh, _Float16* __restrict__ Wbh,
    _Float16* __restrict__ wx12h, _Float16* __restrict__ wx3h)
{
    const int NX = NT*IN_/8;          // 1572864 units of 8
    const int NW = H_*IN_/8;          // 65536
    const int NP = H_*512/8;          // 65536 (x-part pack per matrix)
    const int total = 2*NX + NW + 3*NP;
    for (int i = blockIdx.x*blockDim.x + threadIdx.x; i < total; i += gridDim.x*blockDim.x) {
        const float* src; _Float16* dst;
        if (i < NX)            { src = x  + (size_t)i*8;        dst = xh  + (size_t)i*8; }
        else if (i < 2*NX)     { int u=i-NX;    src = td + (size_t)u*8; dst = tdh + (size_t)u*8; }
        else if (i < 2*NX+NW)  { int u=i-2*NX;  src = Wb + (size_t)u*8; dst = Wbh + (size_t)u*8; }
        else if (i < 2*NX+NW+NP)   { int u=i-2*NX-NW;      int row=u>>6, sl=u&63;
            src = W1 + (size_t)row*K1 + 1024 + sl*8; dst = wx12h + (size_t)row*512 + sl*8; }
        else if (i < 2*NX+NW+2*NP) { int u=i-2*NX-NW-NP;   int row=u>>6, sl=u&63;
            src = W2 + (size_t)row*K1 + 1024 + sl*8; dst = wx12h + (size_t)(1024+row)*512 + sl*8; }
        else                       { int u=i-2*NX-NW-2*NP; int row=u>>6, sl=u&63;
            src = W3 + (size_t)row*K1 + 1024 + sl*8; dst = wx3h + (size_t)row*512 + sl*8; }
        float4 a = *(const float4*)src, b = *(const float4*)(src+4);
        f16x8 o;
        o[0]=(_Float16)a.x; o[1]=(_Float16)a.y; o[2]=(_Float16)a.z; o[3]=(_Float16)a.w;
        o[4]=(_Float16)b.x; o[5]=(_Float16)b.y; o[6]=(_Float16)b.z; o[7]=(_Float16)b.w;
        *(f16x8*)dst = o;
    }
}

// ---------------- belta = exp(-relu(td @ Wb^T + bb)) ----------------
__global__ void __launch_bounds__(256) belta_gemm_k(const _Float16* __restrict__ td,
                                                    const _Float16* __restrict__ Wbh,
                                                    const float* __restrict__ bb,
                                                    _Float16* __restrict__ belta) {
    __shared__ _Float16 As[64][136];
    __shared__ _Float16 Bs[128][136];
    const int bid = blockIdx.x;
    const int mt = bid >> 3, nt = bid & 7;
    const int bt0 = mt*64, h0 = nt*128;
    const int tid = threadIdx.x;
    const int w = tid >> 6, l = tid & 63;
    const int wm = (w>>1)*32, wn = (w&1)*64;
    f32x4 acc[2][4] = {};
    for (int kc = 0; kc < 4; ++kc) {
        const int kbase = kc*128;
        #pragma unroll
        for (int p = 0; p < 4; ++p) {
            int unit = tid + 256*p; int r = unit>>4, cu = unit&15;
            *(uint4*)&As[r][cu*8] = *(const uint4*)(td + (size_t)(bt0+r)*IN_ + kbase + cu*8);
        }
        #pragma unroll
        for (int p = 0; p < 8; ++p) {
            int unit = tid + 256*p; int r = unit>>4, cu = unit&15;
            *(uint4*)&Bs[r][cu*8] = *(const uint4*)(Wbh + (size_t)(h0+r)*IN_ + kbase + cu*8);
        }
        __syncthreads();
        #pragma unroll
        for (int ks = 0; ks < 4; ++ks) {
            const int kk = ks*32 + (l>>4)*8;
            f16x8 a0 = *(const f16x8*)&As[wm +      (l&15)][kk];
            f16x8 a1 = *(const f16x8*)&As[wm + 16 + (l&15)][kk];
            #pragma unroll
            for (int ni = 0; ni < 4; ++ni) {
                f16x8 b = *(const f16x8*)&Bs[wn + ni*16 + (l&15)][kk];
                acc[0][ni] = __builtin_amdgcn_mfma_f32_16x16x32_f16(a0, b, acc[0][ni], 0,0,0);
                acc[1][ni] = __builtin_amdgcn_mfma_f32_16x16x32_f16(a1, b, acc[1][ni], 0,0,0);
            }
        }
        __syncthreads();
    }
    #pragma unroll
    for (int mi = 0; mi < 2; ++mi)
    #pragma unroll
    for (int ni = 0; ni < 4; ++ni)
    #pragma unroll
    for (int r = 0; r < 4; ++r) {
        int m_l = wm + mi*16 + (l>>4)*4 + r;
        int n_l = wn + ni*16 + (l&15);
        int bt = bt0 + m_l, h = h0 + n_l;
        float z = acc[mi][ni][r] + bb[h];
        belta[(size_t)bt*H_ + h] = (_Float16)__expf(-fmaxf(z, 0.f));
    }
}

// ---------------- Xc = x @ Wx^T + bias (f16 out), N = 2048 or 1024 ----------------
__global__ void __launch_bounds__(256) xc_gemm_k(const _Float16* __restrict__ A,
                                                 const _Float16* __restrict__ Bh,
                                                 const float* __restrict__ bias0,
                                                 const float* __restrict__ bias1,
                                                 _Float16* __restrict__ out,
                                                 int N, int nblk) {
    __shared__ _Float16 As[64][136];
    __shared__ _Float16 Bs[128][136];
    const int bid = blockIdx.x;
    const int mt = bid / nblk, nt = bid - mt*nblk;
    const int bt0 = mt*64, h0 = nt*128;
    const int tid = threadIdx.x;
    const int w = tid >> 6, l = tid & 63;
    const int wm = (w>>1)*32, wn = (w&1)*64;
    f32x4 acc[2][4] = {};
    for (int kc = 0; kc < 4; ++kc) {
        const int kbase = kc*128;
        #pragma unroll
        for (int p = 0; p < 4; ++p) {
            int unit = tid + 256*p; int r = unit>>4, cu = unit&15;
            *(uint4*)&As[r][cu*8] = *(const uint4*)(A + (size_t)(bt0+r)*IN_ + kbase + cu*8);
        }
        #pragma unroll
        for (int p = 0; p < 8; ++p) {
            int unit = tid + 256*p; int r = unit>>4, cu = unit&15;
            *(uint4*)&Bs[r][cu*8] = *(const uint4*)(Bh + (size_t)(h0+r)*IN_ + kbase + cu*8);
        }
        __syncthreads();
        #pragma unroll
        for (int ks = 0; ks < 4; ++ks) {
            const int kk = ks*32 + (l>>4)*8;
            f16x8 a0 = *(const f16x8*)&As[wm +      (l&15)][kk];
            f16x8 a1 = *(const f16x8*)&As[wm + 16 + (l&15)][kk];
            #pragma unroll
            for (int ni = 0; ni < 4; ++ni) {
                f16x8 b = *(const f16x8*)&Bs[wn + ni*16 + (l&15)][kk];
                acc[0][ni] = __builtin_amdgcn_mfma_f32_16x16x32_f16(a0, b, acc[0][ni], 0,0,0);
                acc[1][ni] = __builtin_amdgcn_mfma_f32_16x16x32_f16(a1, b, acc[1][ni], 0,0,0);
            }
        }
        __syncthreads();
    }
    #pragma unroll
    for (int mi = 0; mi < 2; ++mi)
    #pragma unroll
    for (int ni = 0; ni < 4; ++ni)
    #pragma unroll
    for (int r = 0; r < 4; ++r) {
        int m_l = wm + mi*16 + (l>>4)*4 + r;
        int n_l = wn + ni*16 + (l&15);
        int bt = bt0 + m_l, h = h0 + n_l;
        float z = acc[mi][ni][r] + (h < 1024 ? bias0[h] : bias1[h-1024]);
        out[(size_t)bt*N + h] = (_Float16)z;
    }
}

// ---------------- XCD-local barrier: one 128-B line per flag ----------------
#define FSTR 32   // ints per flag slot (128 B)
__device__ __forceinline__ void group_barrier32(int* flags, int gbase, int j, int it) {
    waitv0_();                 // data stores committed before publishing
    __syncthreads();
    if (threadIdx.x == 0)
        __hip_atomic_store(&flags[(gbase + j)*FSTR], it,
                           __ATOMIC_RELAXED, __HIP_MEMORY_SCOPE_AGENT);
    for (;;) {
        int v = __hip_atomic_load(&flags[(gbase + (threadIdx.x & 31))*FSTR],
                                  __ATOMIC_RELAXED, __HIP_MEMORY_SCOPE_AGENT);
        if (__syncthreads_count(v < it) == 0) break;
        __builtin_amdgcn_s_sleep(1);
    }
    __builtin_amdgcn_sched_barrier(0);   // keep prefetch-register uses after the drain
}

// ---------------- recurrent scan: XCD-local, P1 fp8 / P2 f16, prefetched scalars ----------------
__global__ void __launch_bounds__(256, 1) recur_k(
    const _Float16* __restrict__ belh,   // (B,T,H)
    const float* __restrict__ W1, const float* __restrict__ W2, const float* __restrict__ W3,
    const _Float16* __restrict__ xc12,   // (B*T, 2048): x@W12x^T + b (u|r)
    const _Float16* __restrict__ xc3,    // (B*T, 1024): x@W3x^T + b3
    const float* __restrict__ Wo,
    unsigned char* __restrict__ ssh,     // (256,1024) fp8 scaled state — L2 exchange
    _Float16* __restrict__ rsh,          // (256,1024) f16 r*state — L2 exchange
    int* flags, int* claim, float* __restrict__ outacc)
{
    __shared__ __align__(16) char smem[131072];
    __shared__ int sh_gid[2];
    const int tid = threadIdx.x;
    if (tid == 0) {
        int xcd;
        asm volatile("s_getreg_b32 %0, hwreg(HW_REG_XCC_ID)" : "=s"(xcd));
        xcd &= 7;
        sh_gid[0] = xcd;
        sh_gid[1] = atomicAdd(&claim[xcd*64], 1) & 31;   // claim also line-padded
    }
    __syncthreads();
    const int g = sh_gid[0], j = sh_gid[1];
    const int gbase = g*32, grow0 = g*32;
    const int w = tid >> 6, l = tid & 63;
    const int lh = l >> 4, ll = l & 15;
    const int mi = w >> 1, nc = w & 1;   // wave = (M-frag, N-half)

    // ---- LDS fill: W12 state-part fp8 x8 (64 rows x 128 k8-slots, k-major) ----
    for (int u = tid; u < 64*128; u += 256) {
        int row = u >> 7, slot = u & 127;
        const float* src = (row < 32 ? W1 + (size_t)(32*j + row)*K1
                                     : W2 + (size_t)(32*j + row-32)*K1) + slot*8;
        unsigned lo = 0, hi = 0;
        lo = __builtin_amdgcn_cvt_pk_fp8_f32(src[0]*8.f, src[1]*8.f, lo, false);
        lo = __builtin_amdgcn_cvt_pk_fp8_f32(src[2]*8.f, src[3]*8.f, lo, true);
        hi = __builtin_amdgcn_cvt_pk_fp8_f32(src[4]*8.f, src[5]*8.f, hi, false);
        hi = __builtin_amdgcn_cvt_pk_fp8_f32(src[6]*8.f, src[7]*8.f, hi, true);
        uint2 o; o.x = lo; o.y = hi;
        *(uint2*)(smem + W12S_OFF + ((size_t)slot*64 + row)*8) = o;
    }
    // ---- W3 state-part f16 (32 rows x 128 k8-slots, k-major) ----
    for (int u = tid; u < 32*128; u += 256) {
        int row = u >> 7, slot = u & 127;
        const float* src = W3 + (size_t)(32*j + row)*K1 + slot*8;
        float4 f0 = *(const float4*)src, f1 = *(const float4*)(src+4);
        f16x8 h;
        h[0]=(_Float16)f0.x; h[1]=(_Float16)f0.y; h[2]=(_Float16)f0.z; h[3]=(_Float16)f0.w;
        h[4]=(_Float16)f1.x; h[5]=(_Float16)f1.y; h[6]=(_Float16)f1.z; h[7]=(_Float16)f1.w;
        *(f16x8*)(smem + W3S_OFF + ((size_t)slot*32 + row)*16) = h;
    }
    __syncthreads();

    const int colU = j*32 + nc*16 + ll;              // owned output column
    const float woc = Wo[colU];
    const int crow0 = grow0 + mi*16 + lh*4;          // epilogue rows (+r)

    // per-lane A bases: row = grow0 + mi*16 + ll, k-offset lh*8
    const unsigned char* srow_s = ssh + ((size_t)(grow0 + mi*16 + ll) << 10) + lh*8;  // fp8
    const _Float16*      srow_r = rsh + ((size_t)(grow0 + mi*16 + ll) << 10) + lh*8;  // f16

    float S_reg[4] = {0.f,0.f,0.f,0.f};
    float pout[4]  = {0.f,0.f,0.f,0.f};
    int it = 0;

    #define SEC1(S, AB) do { \
        _Pragma("unroll") for (int kf = 0; kf < 4; ++kf) { \
            const int kx = (S)*4 + kf; \
            long long a = __builtin_bit_cast(long long, AB[kx]); \
            long long bu = __builtin_bit_cast(long long, \
                *(const uint2*)(smem + W12S_OFF + (((kx*4+lh)*64) + nc*16 + ll)*8)); \
            long long br = __builtin_bit_cast(long long, \
                *(const uint2*)(smem + W12S_OFF + (((kx*4+lh)*64) + 32 + nc*16 + ll)*8)); \
            accu = __builtin_amdgcn_mfma_f32_16x16x32_fp8_fp8(a, bu, accu, 0,0,0); \
            accr = __builtin_amdgcn_mfma_f32_16x16x32_fp8_fp8(a, br, accr, 0,0,0); \
        } } while(0)
    #define SEC2(S, AB) do { \
        _Pragma("unroll") for (int kf = 0; kf < 4; ++kf) { \
            const int kx = (S)*4 + kf; \
            f16x8 a = *(const f16x8*)&AB[kx]; \
            f16x8 b = *(const f16x8*)(smem + W3S_OFF + (((kx*4+lh)*32) + nc*16 + ll)*16); \
            acc2 = __builtin_amdgcn_mfma_f32_16x16x32_f16(a, b, acc2, 0,0,0); \
        } } while(0)

    // ---- prologue prefetch: xcu/xcr for t=0 ----
    unsigned xcu[4], xcr[4];
    #pragma unroll
    for (int r = 0; r < 4; ++r)
        xcu[r] = ld_u16p(xc12 + ((size_t)(crow0 + r)*T_)*2048 + colU);
    #pragma unroll
    for (int r = 0; r < 4; ++r)
        xcr[r] = ld_u16p(xc12 + ((size_t)(crow0 + r)*T_)*2048 + 1024 + colU);
    waitv0_();

    for (int t = 0; t < T_; ++t) {
        const int tn = (t < T_-1) ? t+1 : t;
        float u_reg[4];
        unsigned xc3v[4], bv[4];
        { // ---- P1: u,r = sigmoid(0.125*(fp8 s @ fp8 8*W12s^T) + Xc12) ----
            uint2 ab1[32];                           // fp8 A frags (64 VGPR)
            #pragma unroll
            for (int k2 = 0; k2 < 32; ++k2)
                ab1[k2] = ld_l2_b64(srow_s + k2*32);
            // prefetch (youngest in FIFO): xc3/bel for this step's P2
            #pragma unroll
            for (int r = 0; r < 4; ++r)
                xc3v[r] = ld_u16p(xc3 + ((size_t)(crow0 + r)*T_ + t)*1024 + colU);
            #pragma unroll
            for (int r = 0; r < 4; ++r)
                bv[r] = ld_u16p(belh + ((size_t)(crow0 + r)*T_ + tn)*H_ + colU);
            f32x4 accu = {}, accr = {};
            WAITV(36); SEC1(0, ab1);
            WAITV(32); SEC1(1, ab1);
            WAITV(28); SEC1(2, ab1);
            WAITV(24); SEC1(3, ab1);
            WAITV(20); SEC1(4, ab1);
            WAITV(16); SEC1(5, ab1);
            WAITV(12); SEC1(6, ab1);
            WAITV(8);  SEC1(7, ab1);
            #pragma unroll
            for (int r = 0; r < 4; ++r) {            // uses xcu/xcr from prev phase
                unsigned short uu16 = (unsigned short)xcu[r], rr16 = (unsigned short)xcr[r];
                float uu = sigmoidf_(accu[r]*0.125f + (float)(*(_Float16*)&uu16));
                float rr = sigmoidf_(accr[r]*0.125f + (float)(*(_Float16*)&rr16));
                u_reg[r] = uu;
                _Float16 hv = (_Float16)(rr * S_reg[r]);
                st_l2_u16(rsh + ((size_t)(crow0 + r) << 10) + colU,
                          (unsigned)*(unsigned short*)&hv);
            }
        }
        group_barrier32(flags, gbase, j, ++it);      // drains prefetch into regs
        { // ---- P2: ns = tanh((f16 r*s @ f16 W3s^T) + Xc3); state update ----
            uint4 ab2[32];                           // f16 A frags (128 VGPR)
            #pragma unroll
            for (int k2 = 0; k2 < 32; ++k2)
                ab2[k2] = ld_l2_b128(srow_r + k2*32);
            // prefetch (youngest): xc12 for next step's P1
            #pragma unroll
            for (int r = 0; r < 4; ++r)
                xcu[r] = ld_u16p(xc12 + ((size_t)(crow0 + r)*T_ + tn)*2048 + colU);
            #pragma unroll
            for (int r = 0; r < 4; ++r)
                xcr[r] = ld_u16p(xc12 + ((size_t)(crow0 + r)*T_ + tn)*2048 + 1024 + colU);
            f32x4 acc2 = {};
            WAITV(36); SEC2(0, ab2);
            WAITV(32); SEC2(1, ab2);
            WAITV(28); SEC2(2, ab2);
            WAITV(24); SEC2(3, ab2);
            WAITV(20); SEC2(4, ab2);
            WAITV(16); SEC2(5, ab2);
            WAITV(12); SEC2(6, ab2);
            WAITV(8);  SEC2(7, ab2);
            #pragma unroll
            for (int r = 0; r < 4; ++r) {            // uses xc3v/bv from P1 prefetch
                unsigned short x16 = (unsigned short)xc3v[r];
                float ns = tanhf_(acc2[r] + (float)(*(_Float16*)&x16));
                float sn = (1.f - u_reg[r])*S_reg[r] + u_reg[r]*ns;
                if (t < T_-1) {
                    unsigned short us = (unsigned short)bv[r];
                    float bel = (float)(*(_Float16*)&us);
                    float ss = bel * sn;
                    S_reg[r] = ss;
                    st_l2_u8(ssh + ((size_t)(crow0 + r) << 10) + colU, to_fp8(ss));
                } else {
                    pout[r] = sn * woc;
                }
            }
        }
        group_barrier32(flags, gbase, j, ++it);
    }
    #undef SEC1
    #undef SEC2
    // ---- final: sum pout over this wave's 16 cols, atomicAdd per row ----
    #pragma unroll
    for (int r = 0; r < 4; ++r) {
        float v = pout[r];
        v += __shfl_xor(v, 1, 64);
        v += __shfl_xor(v, 2, 64);
        v += __shfl_xor(v, 4, 64);
        v += __shfl_xor(v, 8, 64);
        if (ll == 0) atomicAdd(&outacc[crow0 + r], v);
    }
}

__global__ void finish_k(const float* __restrict__ acc, const float* __restrict__ bo,
                         float* __restrict__ out) {
    int i = threadIdx.x;
    out[i] = sigmoidf_(acc[i] + bo[0]);
}

extern "C" void kernel_launch(void* const* d_in, const int* in_sizes, int n_in,
                              void* d_out, int out_size, void* d_ws, size_t ws_size,
                              hipStream_t stream) {
    const float* x   = (const float*)d_in[0];
    const float* td  = (const float*)d_in[1];
    const float* Wb  = (const float*)d_in[2];
    const float* bb  = (const float*)d_in[3];
    const float* W1  = (const float*)d_in[4];
    const float* b1  = (const float*)d_in[5];
    const float* W2  = (const float*)d_in[6];
    const float* b2  = (const float*)d_in[7];
    const float* W3  = (const float*)d_in[8];
    const float* b3  = (const float*)d_in[9];
    const float* Wo  = (const float*)d_in[10];
    const float* bo  = (const float*)d_in[11];
    float* out = (float*)d_out;

    char* p = (char*)d_ws;
    auto carve = [&](size_t bytes) { char* r = p; p += (bytes + 255) & ~(size_t)255; return r; };
    int*           bar    = (int*)           carve(32768);             // 256 flag-lines x 128 B
    int*           claim  = (int*)           carve(2048);              // 8 XCD counters, line-padded
    float*         outacc = (float*)         carve(1024);              // 256 partial sums
    unsigned char* ssh    = (unsigned char*) carve((size_t)B_*H_);     // fp8 state exchange
    _Float16*      rsh    = (_Float16*)      carve((size_t)B_*H_*2);   // f16 r*state exchange
    _Float16*      xh     = (_Float16*)      carve((size_t)NT*IN_*2);
    _Float16*      tdh    = (_Float16*)      carve((size_t)NT*IN_*2);
    _Float16*      belh   = (_Float16*)      carve((size_t)NT*H_*2);
    _Float16*      Wbh    = (_Float16*)      carve((size_t)H_*IN_*2);
    _Float16*      wx12h  = (_Float16*)      carve((size_t)2048*512*2);
    _Float16*      wx3h   = (_Float16*)      carve((size_t)1024*512*2);
    _Float16*      xc12   = (_Float16*)      carve((size_t)NT*2048*2); // 100.7 MB
    _Float16*      xc3    = (_Float16*)      carve((size_t)NT*1024*2); // 50.3 MB

    // zero: flags + claim + outacc + ssh (contiguous at front)
    size_t zbytes = 32768 + 2048 + 1024 + (size_t)B_*H_;
    (void)hipMemsetAsync(bar, 0, zbytes, stream);

    prep_cvt_k<<<2048, 256, 0, stream>>>(x, td, Wb, W1, W2, W3,
                                         xh, tdh, Wbh, wx12h, wx3h);

    belta_gemm_k<<<(NT/64)*(H_/128), 256, 0, stream>>>(tdh, Wbh, bb, belh);
    xc_gemm_k<<<(NT/64)*(2048/128), 256, 0, stream>>>(xh, wx12h, b1, b2, xc12, 2048, 16);
    xc_gemm_k<<<(NT/64)*(1024/128), 256, 0, stream>>>(xh, wx3h,  b3, b3, xc3,  1024, 8);

    recur_k<<<256, 256, 0, stream>>>(belh, W1, W2, W3, xc12, xc3, Wo,
                                     ssh, rsh, bar, claim, outacc);
    finish_k<<<1, 256, 0, stream>>>(outacc, bo, out);
}

// Round 19
// 1257.304 us; speedup vs baseline: 2.0263x; 1.0778x over previous
//
#include <hip/hip_runtime.h>
#include <hip/hip_fp16.h>

#define B_  256
#define T_  96
#define IN_ 512
#define H_  1024
#define K1  1536          // H + IN
#define NT  (B_*T_)       // 24576

// recur_k: 8 XCD-groups x 32 blocks (runtime XCC_ID). Group owns 32 batch rows;
// block owns 32 cols. x-part precomputed (Xc12/Xc3).
// P1: fp8 state exchange (ssh) x fp8 W12s(x8) -> native fp8 MFMA (scale 0.125).
// P2: f16 r*s exchange (rsh) x f16 W3s -> f16 MFMA.
// r17: xc/bel prefetched one phase ahead. r18: 128B-line-padded flags.
// r19: barrier polls with ONE wave (32 lanes) — 8x less coherence-point traffic.
#define W12S_OFF 0        // fp8: ((k8*64 + row))*8 ; 65536 B
#define W3S_OFF  65536    // f16: ((k8*32 + row))*16 ; 65536 B -> total 131072 B

typedef _Float16 f16x8 __attribute__((ext_vector_type(8)));
typedef float    f32x4 __attribute__((ext_vector_type(4)));

__device__ __forceinline__ float sigmoidf_(float z) { return 1.f/(1.f+__expf(-z)); }
__device__ __forceinline__ float tanhf_(float z)    { return 1.f - 2.f/(__expf(2.f*z)+1.f); }

// sc0 data path = bypass L1, served by this XCD's L2 (r14-proven for data)
__device__ __forceinline__ uint2 ld_l2_b64(const void* p){
    uint2 r; asm volatile("global_load_dwordx2 %0, %1, off sc0" : "=&v"(r) : "v"(p)); return r;
}
__device__ __forceinline__ uint4 ld_l2_b128(const void* p){
    uint4 r; asm volatile("global_load_dwordx4 %0, %1, off sc0" : "=&v"(r) : "v"(p)); return r;
}
__device__ __forceinline__ unsigned ld_u16p(const void* p){
    unsigned r; asm volatile("global_load_ushort %0, %1, off" : "=&v"(r) : "v"(p)); return r;
}
__device__ __forceinline__ void st_l2_u8(void* p, unsigned v){
    asm volatile("global_store_byte %0, %1, off sc0" :: "v"(p), "v"(v) : "memory");
}
__device__ __forceinline__ void st_l2_u16(void* p, unsigned v){
    asm volatile("global_store_short %0, %1, off sc0" :: "v"(p), "v"(v) : "memory");
}
#define WAITV(n) do { asm volatile("s_waitcnt vmcnt(" #n ")" ::: "memory"); \
                      __builtin_amdgcn_sched_barrier(0); } while(0)
__device__ __forceinline__ void waitv0_(){ asm volatile("s_waitcnt vmcnt(0)" ::: "memory"); }

__device__ __forceinline__ unsigned to_fp8(float x){
    return (unsigned)__builtin_amdgcn_cvt_pk_fp8_f32(x, x, 0, false) & 0xFFu;
}

// ---------------- fused prep: all f32->f16 conversions in one kernel ----------------
__global__ void __launch_bounds__(256) prep_cvt_k(
    const float* __restrict__ x, const float* __restrict__ td, const float* __restrict__ Wb,
    const float* __restrict__ W1, const float* __restrict__ W2, const float* __restrict__ W3,
    _Float16* __restrict__ xh, _Float16* __restrict__ tdh, _Float16* __restrict__ Wbh,
    _Float16* __restrict__ wx12h, _Float16* __restrict__ wx3h)
{
    const int NX = NT*IN_/8;          // 1572864 units of 8
    const int NW = H_*IN_/8;          // 65536
    const int NP = H_*512/8;          // 65536 (x-part pack per matrix)
    const int total = 2*NX + NW + 3*NP;
    for (int i = blockIdx.x*blockDim.x + threadIdx.x; i < total; i += gridDim.x*blockDim.x) {
        const float* src; _Float16* dst;
        if (i < NX)            { src = x  + (size_t)i*8;        dst = xh  + (size_t)i*8; }
        else if (i < 2*NX)     { int u=i-NX;    src = td + (size_t)u*8; dst = tdh + (size_t)u*8; }
        else if (i < 2*NX+NW)  { int u=i-2*NX;  src = Wb + (size_t)u*8; dst = Wbh + (size_t)u*8; }
        else if (i < 2*NX+NW+NP)   { int u=i-2*NX-NW;      int row=u>>6, sl=u&63;
            src = W1 + (size_t)row*K1 + 1024 + sl*8; dst = wx12h + (size_t)row*512 + sl*8; }
        else if (i < 2*NX+NW+2*NP) { int u=i-2*NX-NW-NP;   int row=u>>6, sl=u&63;
            src = W2 + (size_t)row*K1 + 1024 + sl*8; dst = wx12h + (size_t)(1024+row)*512 + sl*8; }
        else                       { int u=i-2*NX-NW-2*NP; int row=u>>6, sl=u&63;
            src = W3 + (size_t)row*K1 + 1024 + sl*8; dst = wx3h + (size_t)row*512 + sl*8; }
        float4 a = *(const float4*)src, b = *(const float4*)(src+4);
        f16x8 o;
        o[0]=(_Float16)a.x; o[1]=(_Float16)a.y; o[2]=(_Float16)a.z; o[3]=(_Float16)a.w;
        o[4]=(_Float16)b.x; o[5]=(_Float16)b.y; o[6]=(_Float16)b.z; o[7]=(_Float16)b.w;
        *(f16x8*)dst = o;
    }
}

// ---------------- belta = exp(-relu(td @ Wb^T + bb)) ----------------
__global__ void __launch_bounds__(256) belta_gemm_k(const _Float16* __restrict__ td,
                                                    const _Float16* __restrict__ Wbh,
                                                    const float* __restrict__ bb,
                                                    _Float16* __restrict__ belta) {
    __shared__ _Float16 As[64][136];
    __shared__ _Float16 Bs[128][136];
    const int bid = blockIdx.x;
    const int mt = bid >> 3, nt = bid & 7;
    const int bt0 = mt*64, h0 = nt*128;
    const int tid = threadIdx.x;
    const int w = tid >> 6, l = tid & 63;
    const int wm = (w>>1)*32, wn = (w&1)*64;
    f32x4 acc[2][4] = {};
    for (int kc = 0; kc < 4; ++kc) {
        const int kbase = kc*128;
        #pragma unroll
        for (int p = 0; p < 4; ++p) {
            int unit = tid + 256*p; int r = unit>>4, cu = unit&15;
            *(uint4*)&As[r][cu*8] = *(const uint4*)(td + (size_t)(bt0+r)*IN_ + kbase + cu*8);
        }
        #pragma unroll
        for (int p = 0; p < 8; ++p) {
            int unit = tid + 256*p; int r = unit>>4, cu = unit&15;
            *(uint4*)&Bs[r][cu*8] = *(const uint4*)(Wbh + (size_t)(h0+r)*IN_ + kbase + cu*8);
        }
        __syncthreads();
        #pragma unroll
        for (int ks = 0; ks < 4; ++ks) {
            const int kk = ks*32 + (l>>4)*8;
            f16x8 a0 = *(const f16x8*)&As[wm +      (l&15)][kk];
            f16x8 a1 = *(const f16x8*)&As[wm + 16 + (l&15)][kk];
            #pragma unroll
            for (int ni = 0; ni < 4; ++ni) {
                f16x8 b = *(const f16x8*)&Bs[wn + ni*16 + (l&15)][kk];
                acc[0][ni] = __builtin_amdgcn_mfma_f32_16x16x32_f16(a0, b, acc[0][ni], 0,0,0);
                acc[1][ni] = __builtin_amdgcn_mfma_f32_16x16x32_f16(a1, b, acc[1][ni], 0,0,0);
            }
        }
        __syncthreads();
    }
    #pragma unroll
    for (int mi = 0; mi < 2; ++mi)
    #pragma unroll
    for (int ni = 0; ni < 4; ++ni)
    #pragma unroll
    for (int r = 0; r < 4; ++r) {
        int m_l = wm + mi*16 + (l>>4)*4 + r;
        int n_l = wn + ni*16 + (l&15);
        int bt = bt0 + m_l, h = h0 + n_l;
        float z = acc[mi][ni][r] + bb[h];
        belta[(size_t)bt*H_ + h] = (_Float16)__expf(-fmaxf(z, 0.f));
    }
}

// ---------------- Xc = x @ Wx^T + bias (f16 out), N = 2048 or 1024 ----------------
__global__ void __launch_bounds__(256) xc_gemm_k(const _Float16* __restrict__ A,
                                                 const _Float16* __restrict__ Bh,
                                                 const float* __restrict__ bias0,
                                                 const float* __restrict__ bias1,
                                                 _Float16* __restrict__ out,
                                                 int N, int nblk) {
    __shared__ _Float16 As[64][136];
    __shared__ _Float16 Bs[128][136];
    const int bid = blockIdx.x;
    const int mt = bid / nblk, nt = bid - mt*nblk;
    const int bt0 = mt*64, h0 = nt*128;
    const int tid = threadIdx.x;
    const int w = tid >> 6, l = tid & 63;
    const int wm = (w>>1)*32, wn = (w&1)*64;
    f32x4 acc[2][4] = {};
    for (int kc = 0; kc < 4; ++kc) {
        const int kbase = kc*128;
        #pragma unroll
        for (int p = 0; p < 4; ++p) {
            int unit = tid + 256*p; int r = unit>>4, cu = unit&15;
            *(uint4*)&As[r][cu*8] = *(const uint4*)(A + (size_t)(bt0+r)*IN_ + kbase + cu*8);
        }
        #pragma unroll
        for (int p = 0; p < 8; ++p) {
            int unit = tid + 256*p; int r = unit>>4, cu = unit&15;
            *(uint4*)&Bs[r][cu*8] = *(const uint4*)(Bh + (size_t)(h0+r)*IN_ + kbase + cu*8);
        }
        __syncthreads();
        #pragma unroll
        for (int ks = 0; ks < 4; ++ks) {
            const int kk = ks*32 + (l>>4)*8;
            f16x8 a0 = *(const f16x8*)&As[wm +      (l&15)][kk];
            f16x8 a1 = *(const f16x8*)&As[wm + 16 + (l&15)][kk];
            #pragma unroll
            for (int ni = 0; ni < 4; ++ni) {
                f16x8 b = *(const f16x8*)&Bs[wn + ni*16 + (l&15)][kk];
                acc[0][ni] = __builtin_amdgcn_mfma_f32_16x16x32_f16(a0, b, acc[0][ni], 0,0,0);
                acc[1][ni] = __builtin_amdgcn_mfma_f32_16x16x32_f16(a1, b, acc[1][ni], 0,0,0);
            }
        }
        __syncthreads();
    }
    #pragma unroll
    for (int mi = 0; mi < 2; ++mi)
    #pragma unroll
    for (int ni = 0; ni < 4; ++ni)
    #pragma unroll
    for (int r = 0; r < 4; ++r) {
        int m_l = wm + mi*16 + (l>>4)*4 + r;
        int n_l = wn + ni*16 + (l&15);
        int bt = bt0 + m_l, h = h0 + n_l;
        float z = acc[mi][ni][r] + (h < 1024 ? bias0[h] : bias1[h-1024]);
        out[(size_t)bt*N + h] = (_Float16)z;
    }
}

// ---------------- XCD-local barrier: 1 line/flag, single-wave poll ----------------
#define FSTR 32   // ints per flag slot (128 B)
__device__ __forceinline__ void group_barrier32(int* flags, int gbase, int j, int it,
                                                int w, int l) {
    waitv0_();                 // data stores committed before publishing
    __syncthreads();
    if (threadIdx.x == 0)
        __hip_atomic_store(&flags[(gbase + j)*FSTR], it,
                           __ATOMIC_RELAXED, __HIP_MEMORY_SCOPE_AGENT);
    if (w == 0) {              // only wave 0 polls: 32 lanes, 8x less traffic
        for (;;) {
            int v = it;
            if (l < 32)
                v = __hip_atomic_load(&flags[(gbase + l)*FSTR],
                                      __ATOMIC_RELAXED, __HIP_MEMORY_SCOPE_AGENT);
            if (__all(v >= it)) break;
            __builtin_amdgcn_s_sleep(2);
        }
    }
    __syncthreads();           // release waves 1-3
    __builtin_amdgcn_sched_barrier(0);
}

// ---------------- recurrent scan: XCD-local, P1 fp8 / P2 f16, prefetched scalars ----------------
__global__ void __launch_bounds__(256, 1) recur_k(
    const _Float16* __restrict__ belh,   // (B,T,H)
    const float* __restrict__ W1, const float* __restrict__ W2, const float* __restrict__ W3,
    const _Float16* __restrict__ xc12,   // (B*T, 2048): x@W12x^T + b (u|r)
    const _Float16* __restrict__ xc3,    // (B*T, 1024): x@W3x^T + b3
    const float* __restrict__ Wo,
    unsigned char* __restrict__ ssh,     // (256,1024) fp8 scaled state — L2 exchange
    _Float16* __restrict__ rsh,          // (256,1024) f16 r*state — L2 exchange
    int* flags, int* claim, float* __restrict__ outacc)
{
    __shared__ __align__(16) char smem[131072];
    __shared__ int sh_gid[2];
    const int tid = threadIdx.x;
    if (tid == 0) {
        int xcd;
        asm volatile("s_getreg_b32 %0, hwreg(HW_REG_XCC_ID)" : "=s"(xcd));
        xcd &= 7;
        sh_gid[0] = xcd;
        sh_gid[1] = atomicAdd(&claim[xcd*64], 1) & 31;   // claim line-padded
    }
    __syncthreads();
    const int g = sh_gid[0], j = sh_gid[1];
    const int gbase = g*32, grow0 = g*32;
    const int w = tid >> 6, l = tid & 63;
    const int lh = l >> 4, ll = l & 15;
    const int mi = w >> 1, nc = w & 1;   // wave = (M-frag, N-half)

    // ---- LDS fill: W12 state-part fp8 x8 (64 rows x 128 k8-slots, k-major) ----
    for (int u = tid; u < 64*128; u += 256) {
        int row = u >> 7, slot = u & 127;
        const float* src = (row < 32 ? W1 + (size_t)(32*j + row)*K1
                                     : W2 + (size_t)(32*j + row-32)*K1) + slot*8;
        unsigned lo = 0, hi = 0;
        lo = __builtin_amdgcn_cvt_pk_fp8_f32(src[0]*8.f, src[1]*8.f, lo, false);
        lo = __builtin_amdgcn_cvt_pk_fp8_f32(src[2]*8.f, src[3]*8.f, lo, true);
        hi = __builtin_amdgcn_cvt_pk_fp8_f32(src[4]*8.f, src[5]*8.f, hi, false);
        hi = __builtin_amdgcn_cvt_pk_fp8_f32(src[6]*8.f, src[7]*8.f, hi, true);
        uint2 o; o.x = lo; o.y = hi;
        *(uint2*)(smem + W12S_OFF + ((size_t)slot*64 + row)*8) = o;
    }
    // ---- W3 state-part f16 (32 rows x 128 k8-slots, k-major) ----
    for (int u = tid; u < 32*128; u += 256) {
        int row = u >> 7, slot = u & 127;
        const float* src = W3 + (size_t)(32*j + row)*K1 + slot*8;
        float4 f0 = *(const float4*)src, f1 = *(const float4*)(src+4);
        f16x8 h;
        h[0]=(_Float16)f0.x; h[1]=(_Float16)f0.y; h[2]=(_Float16)f0.z; h[3]=(_Float16)f0.w;
        h[4]=(_Float16)f1.x; h[5]=(_Float16)f1.y; h[6]=(_Float16)f1.z; h[7]=(_Float16)f1.w;
        *(f16x8*)(smem + W3S_OFF + ((size_t)slot*32 + row)*16) = h;
    }
    __syncthreads();

    const int colU = j*32 + nc*16 + ll;              // owned output column
    const float woc = Wo[colU];
    const int crow0 = grow0 + mi*16 + lh*4;          // epilogue rows (+r)

    // per-lane A bases: row = grow0 + mi*16 + ll, k-offset lh*8
    const unsigned char* srow_s = ssh + ((size_t)(grow0 + mi*16 + ll) << 10) + lh*8;  // fp8
    const _Float16*      srow_r = rsh + ((size_t)(grow0 + mi*16 + ll) << 10) + lh*8;  // f16

    float S_reg[4] = {0.f,0.f,0.f,0.f};
    float pout[4]  = {0.f,0.f,0.f,0.f};
    int it = 0;

    #define SEC1(S, AB) do { \
        _Pragma("unroll") for (int kf = 0; kf < 4; ++kf) { \
            const int kx = (S)*4 + kf; \
            long long a = __builtin_bit_cast(long long, AB[kx]); \
            long long bu = __builtin_bit_cast(long long, \
                *(const uint2*)(smem + W12S_OFF + (((kx*4+lh)*64) + nc*16 + ll)*8)); \
            long long br = __builtin_bit_cast(long long, \
                *(const uint2*)(smem + W12S_OFF + (((kx*4+lh)*64) + 32 + nc*16 + ll)*8)); \
            accu = __builtin_amdgcn_mfma_f32_16x16x32_fp8_fp8(a, bu, accu, 0,0,0); \
            accr = __builtin_amdgcn_mfma_f32_16x16x32_fp8_fp8(a, br, accr, 0,0,0); \
        } } while(0)
    #define SEC2(S, AB) do { \
        _Pragma("unroll") for (int kf = 0; kf < 4; ++kf) { \
            const int kx = (S)*4 + kf; \
            f16x8 a = *(const f16x8*)&AB[kx]; \
            f16x8 b = *(const f16x8*)(smem + W3S_OFF + (((kx*4+lh)*32) + nc*16 + ll)*16); \
            acc2 = __builtin_amdgcn_mfma_f32_16x16x32_f16(a, b, acc2, 0,0,0); \
        } } while(0)

    // ---- prologue prefetch: xcu/xcr for t=0 ----
    unsigned xcu[4], xcr[4];
    #pragma unroll
    for (int r = 0; r < 4; ++r)
        xcu[r] = ld_u16p(xc12 + ((size_t)(crow0 + r)*T_)*2048 + colU);
    #pragma unroll
    for (int r = 0; r < 4; ++r)
        xcr[r] = ld_u16p(xc12 + ((size_t)(crow0 + r)*T_)*2048 + 1024 + colU);
    waitv0_();

    for (int t = 0; t < T_; ++t) {
        const int tn = (t < T_-1) ? t+1 : t;
        float u_reg[4];
        unsigned xc3v[4], bv[4];
        { // ---- P1: u,r = sigmoid(0.125*(fp8 s @ fp8 8*W12s^T) + Xc12) ----
            uint2 ab1[32];                           // fp8 A frags (64 VGPR)
            #pragma unroll
            for (int k2 = 0; k2 < 32; ++k2)
                ab1[k2] = ld_l2_b64(srow_s + k2*32);
            // prefetch (youngest in FIFO): xc3/bel for this step's P2
            #pragma unroll
            for (int r = 0; r < 4; ++r)
                xc3v[r] = ld_u16p(xc3 + ((size_t)(crow0 + r)*T_ + t)*1024 + colU);
            #pragma unroll
            for (int r = 0; r < 4; ++r)
                bv[r] = ld_u16p(belh + ((size_t)(crow0 + r)*T_ + tn)*H_ + colU);
            f32x4 accu = {}, accr = {};
            WAITV(36); SEC1(0, ab1);
            WAITV(32); SEC1(1, ab1);
            WAITV(28); SEC1(2, ab1);
            WAITV(24); SEC1(3, ab1);
            WAITV(20); SEC1(4, ab1);
            WAITV(16); SEC1(5, ab1);
            WAITV(12); SEC1(6, ab1);
            WAITV(8);  SEC1(7, ab1);
            #pragma unroll
            for (int r = 0; r < 4; ++r) {            // uses xcu/xcr from prev phase
                unsigned short uu16 = (unsigned short)xcu[r], rr16 = (unsigned short)xcr[r];
                float uu = sigmoidf_(accu[r]*0.125f + (float)(*(_Float16*)&uu16));
                float rr = sigmoidf_(accr[r]*0.125f + (float)(*(_Float16*)&rr16));
                u_reg[r] = uu;
                _Float16 hv = (_Float16)(rr * S_reg[r]);
                st_l2_u16(rsh + ((size_t)(crow0 + r) << 10) + colU,
                          (unsigned)*(unsigned short*)&hv);
            }
        }
        group_barrier32(flags, gbase, j, ++it, w, l);
        { // ---- P2: ns = tanh((f16 r*s @ f16 W3s^T) + Xc3); state update ----
            uint4 ab2[32];                           // f16 A frags (128 VGPR)
            #pragma unroll
            for (int k2 = 0; k2 < 32; ++k2)
                ab2[k2] = ld_l2_b128(srow_r + k2*32);
            // prefetch (youngest): xc12 for next step's P1
            #pragma unroll
            for (int r = 0; r < 4; ++r)
                xcu[r] = ld_u16p(xc12 + ((size_t)(crow0 + r)*T_ + tn)*2048 + colU);
            #pragma unroll
            for (int r = 0; r < 4; ++r)
                xcr[r] = ld_u16p(xc12 + ((size_t)(crow0 + r)*T_ + tn)*2048 + 1024 + colU);
            f32x4 acc2 = {};
            WAITV(36); SEC2(0, ab2);
            WAITV(32); SEC2(1, ab2);
            WAITV(28); SEC2(2, ab2);
            WAITV(24); SEC2(3, ab2);
            WAITV(20); SEC2(4, ab2);
            WAITV(16); SEC2(5, ab2);
            WAITV(12); SEC2(6, ab2);
            WAITV(8);  SEC2(7, ab2);
            #pragma unroll
            for (int r = 0; r < 4; ++r) {            // uses xc3v/bv from P1 prefetch
                unsigned short x16 = (unsigned short)xc3v[r];
                float ns = tanhf_(acc2[r] + (float)(*(_Float16*)&x16));
                float sn = (1.f - u_reg[r])*S_reg[r] + u_reg[r]*ns;
                if (t < T_-1) {
                    unsigned short us = (unsigned short)bv[r];
                    float bel = (float)(*(_Float16*)&us);
                    float ss = bel * sn;
                    S_reg[r] = ss;
                    st_l2_u8(ssh + ((size_t)(crow0 + r) << 10) + colU, to_fp8(ss));
                } else {
                    pout[r] = sn * woc;
                }
            }
        }
        group_barrier32(flags, gbase, j, ++it, w, l);
    }
    #undef SEC1
    #undef SEC2
    // ---- final: sum pout over this wave's 16 cols, atomicAdd per row ----
    #pragma unroll
    for (int r = 0; r < 4; ++r) {
        float v = pout[r];
        v += __shfl_xor(v, 1, 64);
        v += __shfl_xor(v, 2, 64);
        v += __shfl_xor(v, 4, 64);
        v += __shfl_xor(v, 8, 64);
        if (ll == 0) atomicAdd(&outacc[crow0 + r], v);
    }
}

__global__ void finish_k(const float* __restrict__ acc, const float* __restrict__ bo,
                         float* __restrict__ out) {
    int i = threadIdx.x;
    out[i] = sigmoidf_(acc[i] + bo[0]);
}

extern "C" void kernel_launch(void* const* d_in, const int* in_sizes, int n_in,
                              void* d_out, int out_size, void* d_ws, size_t ws_size,
                              hipStream_t stream) {
    const float* x   = (const float*)d_in[0];
    const float* td  = (const float*)d_in[1];
    const float* Wb  = (const float*)d_in[2];
    const float* bb  = (const float*)d_in[3];
    const float* W1  = (const float*)d_in[4];
    const float* b1  = (const float*)d_in[5];
    const float* W2  = (const float*)d_in[6];
    const float* b2  = (const float*)d_in[7];
    const float* W3  = (const float*)d_in[8];
    const float* b3  = (const float*)d_in[9];
    const float* Wo  = (const float*)d_in[10];
    const float* bo  = (const float*)d_in[11];
    float* out = (float*)d_out;

    char* p = (char*)d_ws;
    auto carve = [&](size_t bytes) { char* r = p; p += (bytes + 255) & ~(size_t)255; return r; };
    int*           bar    = (int*)           carve(32768);             // 256 flag-lines x 128 B
    int*           claim  = (int*)           carve(2048);              // 8 XCD counters, line-padded
    float*         outacc = (float*)         carve(1024);              // 256 partial sums
    unsigned char* ssh    = (unsigned char*) carve((size_t)B_*H_);     // fp8 state exchange
    _Float16*      rsh    = (_Float16*)      carve((size_t)B_*H_*2);   // f16 r*state exchange
    _Float16*      xh     = (_Float16*)      carve((size_t)NT*IN_*2);
    _Float16*      tdh    = (_Float16*)      carve((size_t)NT*IN_*2);
    _Float16*      belh   = (_Float16*)      carve((size_t)NT*H_*2);
    _Float16*      Wbh    = (_Float16*)      carve((size_t)H_*IN_*2);
    _Float16*      wx12h  = (_Float16*)      carve((size_t)2048*512*2);
    _Float16*      wx3h   = (_Float16*)      carve((size_t)1024*512*2);
    _Float16*      xc12   = (_Float16*)      carve((size_t)NT*2048*2); // 100.7 MB
    _Float16*      xc3    = (_Float16*)      carve((size_t)NT*1024*2); // 50.3 MB

    // zero: flags + claim + outacc + ssh (contiguous at front)
    size_t zbytes = 32768 + 2048 + 1024 + (size_t)B_*H_;
    (void)hipMemsetAsync(bar, 0, zbytes, stream);

    prep_cvt_k<<<2048, 256, 0, stream>>>(x, td, Wb, W1, W2, W3,
                                         xh, tdh, Wbh, wx12h, wx3h);

    belta_gemm_k<<<(NT/64)*(H_/128), 256, 0, stream>>>(tdh, Wbh, bb, belh);
    xc_gemm_k<<<(NT/64)*(2048/128), 256, 0, stream>>>(xh, wx12h, b1, b2, xc12, 2048, 16);
    xc_gemm_k<<<(NT/64)*(1024/128), 256, 0, stream>>>(xh, wx3h,  b3, b3, xc3,  1024, 8);

    recur_k<<<256, 256, 0, stream>>>(belh, W1, W2, W3, xc12, xc3, Wo,
                                     ssh, rsh, bar, claim, outacc);
    finish_k<<<1, 256, 0, stream>>>(outacc, bo, out);
}

// Round 20
// 1240.020 us; speedup vs baseline: 2.0545x; 1.0139x over previous
//
#include <hip/hip_runtime.h>
#include <hip/hip_fp16.h>

#define B_  256
#define T_  96
#define IN_ 512
#define H_  1024
#define K1  1536          // H + IN
#define NT  (B_*T_)       // 24576

// recur_k: 8 XCD-groups x 32 blocks (runtime XCC_ID). Group owns 32 batch rows;
// block owns 32 cols. x-part precomputed (Xc12/Xc3).
// P1: fp8 ssh x fp8 W12s(x8) -> fp8 MFMA (scale 0.125).
// P2 (r20): fp8 rsh x fp8 W3s(x8) -> fp8 MFMA (scale 0.125).
// r17: scalar streams prefetched a phase ahead. r18: 128B-line flags.
// r19: single-wave poll. r20: sleep-0 poll.
#define W12S_OFF 0        // fp8: ((k8*64 + row))*8 ; 65536 B
#define W3S_OFF  65536    // fp8: ((k8*32 + row))*8 ; 32768 B -> total 98304 B

typedef _Float16 f16x8 __attribute__((ext_vector_type(8)));
typedef float    f32x4 __attribute__((ext_vector_type(4)));

__device__ __forceinline__ float sigmoidf_(float z) { return 1.f/(1.f+__expf(-z)); }
__device__ __forceinline__ float tanhf_(float z)    { return 1.f - 2.f/(__expf(2.f*z)+1.f); }

// sc0 data path = bypass L1, served by this XCD's L2
__device__ __forceinline__ uint2 ld_l2_b64(const void* p){
    uint2 r; asm volatile("global_load_dwordx2 %0, %1, off sc0" : "=&v"(r) : "v"(p)); return r;
}
__device__ __forceinline__ unsigned ld_u16p(const void* p){
    unsigned r; asm volatile("global_load_ushort %0, %1, off" : "=&v"(r) : "v"(p)); return r;
}
__device__ __forceinline__ void st_l2_u8(void* p, unsigned v){
    asm volatile("global_store_byte %0, %1, off sc0" :: "v"(p), "v"(v) : "memory");
}
#define WAITV(n) do { asm volatile("s_waitcnt vmcnt(" #n ")" ::: "memory"); \
                      __builtin_amdgcn_sched_barrier(0); } while(0)
__device__ __forceinline__ void waitv0_(){ asm volatile("s_waitcnt vmcnt(0)" ::: "memory"); }

__device__ __forceinline__ unsigned to_fp8(float x){
    return (unsigned)__builtin_amdgcn_cvt_pk_fp8_f32(x, x, 0, false) & 0xFFu;
}

// ---------------- fused prep: all f32->f16 conversions in one kernel ----------------
__global__ void __launch_bounds__(256) prep_cvt_k(
    const float* __restrict__ x, const float* __restrict__ td, const float* __restrict__ Wb,
    const float* __restrict__ W1, const float* __restrict__ W2, const float* __restrict__ W3,
    _Float16* __restrict__ xh, _Float16* __restrict__ tdh, _Float16* __restrict__ Wbh,
    _Float16* __restrict__ wx12h, _Float16* __restrict__ wx3h)
{
    const int NX = NT*IN_/8;
    const int NW = H_*IN_/8;
    const int NP = H_*512/8;
    const int total = 2*NX + NW + 3*NP;
    for (int i = blockIdx.x*blockDim.x + threadIdx.x; i < total; i += gridDim.x*blockDim.x) {
        const float* src; _Float16* dst;
        if (i < NX)            { src = x  + (size_t)i*8;        dst = xh  + (size_t)i*8; }
        else if (i < 2*NX)     { int u=i-NX;    src = td + (size_t)u*8; dst = tdh + (size_t)u*8; }
        else if (i < 2*NX+NW)  { int u=i-2*NX;  src = Wb + (size_t)u*8; dst = Wbh + (size_t)u*8; }
        else if (i < 2*NX+NW+NP)   { int u=i-2*NX-NW;      int row=u>>6, sl=u&63;
            src = W1 + (size_t)row*K1 + 1024 + sl*8; dst = wx12h + (size_t)row*512 + sl*8; }
        else if (i < 2*NX+NW+2*NP) { int u=i-2*NX-NW-NP;   int row=u>>6, sl=u&63;
            src = W2 + (size_t)row*K1 + 1024 + sl*8; dst = wx12h + (size_t)(1024+row)*512 + sl*8; }
        else                       { int u=i-2*NX-NW-2*NP; int row=u>>6, sl=u&63;
            src = W3 + (size_t)row*K1 + 1024 + sl*8; dst = wx3h + (size_t)row*512 + sl*8; }
        float4 a = *(const float4*)src, b = *(const float4*)(src+4);
        f16x8 o;
        o[0]=(_Float16)a.x; o[1]=(_Float16)a.y; o[2]=(_Float16)a.z; o[3]=(_Float16)a.w;
        o[4]=(_Float16)b.x; o[5]=(_Float16)b.y; o[6]=(_Float16)b.z; o[7]=(_Float16)b.w;
        *(f16x8*)dst = o;
    }
}

// ---------------- belta = exp(-relu(td @ Wb^T + bb)) ----------------
__global__ void __launch_bounds__(256) belta_gemm_k(const _Float16* __restrict__ td,
                                                    const _Float16* __restrict__ Wbh,
                                                    const float* __restrict__ bb,
                                                    _Float16* __restrict__ belta) {
    __shared__ _Float16 As[64][136];
    __shared__ _Float16 Bs[128][136];
    const int bid = blockIdx.x;
    const int mt = bid >> 3, nt = bid & 7;
    const int bt0 = mt*64, h0 = nt*128;
    const int tid = threadIdx.x;
    const int w = tid >> 6, l = tid & 63;
    const int wm = (w>>1)*32, wn = (w&1)*64;
    f32x4 acc[2][4] = {};
    for (int kc = 0; kc < 4; ++kc) {
        const int kbase = kc*128;
        #pragma unroll
        for (int p = 0; p < 4; ++p) {
            int unit = tid + 256*p; int r = unit>>4, cu = unit&15;
            *(uint4*)&As[r][cu*8] = *(const uint4*)(td + (size_t)(bt0+r)*IN_ + kbase + cu*8);
        }
        #pragma unroll
        for (int p = 0; p < 8; ++p) {
            int unit = tid + 256*p; int r = unit>>4, cu = unit&15;
            *(uint4*)&Bs[r][cu*8] = *(const uint4*)(Wbh + (size_t)(h0+r)*IN_ + kbase + cu*8);
        }
        __syncthreads();
        #pragma unroll
        for (int ks = 0; ks < 4; ++ks) {
            const int kk = ks*32 + (l>>4)*8;
            f16x8 a0 = *(const f16x8*)&As[wm +      (l&15)][kk];
            f16x8 a1 = *(const f16x8*)&As[wm + 16 + (l&15)][kk];
            #pragma unroll
            for (int ni = 0; ni < 4; ++ni) {
                f16x8 b = *(const f16x8*)&Bs[wn + ni*16 + (l&15)][kk];
                acc[0][ni] = __builtin_amdgcn_mfma_f32_16x16x32_f16(a0, b, acc[0][ni], 0,0,0);
                acc[1][ni] = __builtin_amdgcn_mfma_f32_16x16x32_f16(a1, b, acc[1][ni], 0,0,0);
            }
        }
        __syncthreads();
    }
    #pragma unroll
    for (int mi = 0; mi < 2; ++mi)
    #pragma unroll
    for (int ni = 0; ni < 4; ++ni)
    #pragma unroll
    for (int r = 0; r < 4; ++r) {
        int m_l = wm + mi*16 + (l>>4)*4 + r;
        int n_l = wn + ni*16 + (l&15);
        int bt = bt0 + m_l, h = h0 + n_l;
        float z = acc[mi][ni][r] + bb[h];
        belta[(size_t)bt*H_ + h] = (_Float16)__expf(-fmaxf(z, 0.f));
    }
}

// ---------------- Xc = x @ Wx^T + bias (f16 out), N = 2048 or 1024 ----------------
__global__ void __launch_bounds__(256) xc_gemm_k(const _Float16* __restrict__ A,
                                                 const _Float16* __restrict__ Bh,
                                                 const float* __restrict__ bias0,
                                                 const float* __restrict__ bias1,
                                                 _Float16* __restrict__ out,
                                                 int N, int nblk) {
    __shared__ _Float16 As[64][136];
    __shared__ _Float16 Bs[128][136];
    const int bid = blockIdx.x;
    const int mt = bid / nblk, nt = bid - mt*nblk;
    const int bt0 = mt*64, h0 = nt*128;
    const int tid = threadIdx.x;
    const int w = tid >> 6, l = tid & 63;
    const int wm = (w>>1)*32, wn = (w&1)*64;
    f32x4 acc[2][4] = {};
    for (int kc = 0; kc < 4; ++kc) {
        const int kbase = kc*128;
        #pragma unroll
        for (int p = 0; p < 4; ++p) {
            int unit = tid + 256*p; int r = unit>>4, cu = unit&15;
            *(uint4*)&As[r][cu*8] = *(const uint4*)(A + (size_t)(bt0+r)*IN_ + kbase + cu*8);
        }
        #pragma unroll
        for (int p = 0; p < 8; ++p) {
            int unit = tid + 256*p; int r = unit>>4, cu = unit&15;
            *(uint4*)&Bs[r][cu*8] = *(const uint4*)(Bh + (size_t)(h0+r)*IN_ + kbase + cu*8);
        }
        __syncthreads();
        #pragma unroll
        for (int ks = 0; ks < 4; ++ks) {
            const int kk = ks*32 + (l>>4)*8;
            f16x8 a0 = *(const f16x8*)&As[wm +      (l&15)][kk];
            f16x8 a1 = *(const f16x8*)&As[wm + 16 + (l&15)][kk];
            #pragma unroll
            for (int ni = 0; ni < 4; ++ni) {
                f16x8 b = *(const f16x8*)&Bs[wn + ni*16 + (l&15)][kk];
                acc[0][ni] = __builtin_amdgcn_mfma_f32_16x16x32_f16(a0, b, acc[0][ni], 0,0,0);
                acc[1][ni] = __builtin_amdgcn_mfma_f32_16x16x32_f16(a1, b, acc[1][ni], 0,0,0);
            }
        }
        __syncthreads();
    }
    #pragma unroll
    for (int mi = 0; mi < 2; ++mi)
    #pragma unroll
    for (int ni = 0; ni < 4; ++ni)
    #pragma unroll
    for (int r = 0; r < 4; ++r) {
        int m_l = wm + mi*16 + (l>>4)*4 + r;
        int n_l = wn + ni*16 + (l&15);
        int bt = bt0 + m_l, h = h0 + n_l;
        float z = acc[mi][ni][r] + (h < 1024 ? bias0[h] : bias1[h-1024]);
        out[(size_t)bt*N + h] = (_Float16)z;
    }
}

// ---------------- XCD-local barrier: 1 line/flag, single-wave poll, no sleep ----------------
#define FSTR 32   // ints per flag slot (128 B)
__device__ __forceinline__ void group_barrier32(int* flags, int gbase, int j, int it,
                                                int w, int l) {
    waitv0_();
    __syncthreads();
    if (threadIdx.x == 0)
        __hip_atomic_store(&flags[(gbase + j)*FSTR], it,
                           __ATOMIC_RELAXED, __HIP_MEMORY_SCOPE_AGENT);
    if (w == 0) {
        for (;;) {
            int v = it;
            if (l < 32)
                v = __hip_atomic_load(&flags[(gbase + l)*FSTR],
                                      __ATOMIC_RELAXED, __HIP_MEMORY_SCOPE_AGENT);
            if (__all(v >= it)) break;
        }
    }
    __syncthreads();
    __builtin_amdgcn_sched_barrier(0);
}

// ---------------- recurrent scan: XCD-local, all-fp8, prefetched scalars ----------------
__global__ void __launch_bounds__(256, 1) recur_k(
    const _Float16* __restrict__ belh,   // (B,T,H)
    const float* __restrict__ W1, const float* __restrict__ W2, const float* __restrict__ W3,
    const _Float16* __restrict__ xc12,   // (B*T, 2048): x@W12x^T + b (u|r)
    const _Float16* __restrict__ xc3,    // (B*T, 1024): x@W3x^T + b3
    const float* __restrict__ Wo,
    unsigned char* __restrict__ ssh,     // (256,1024) fp8 scaled state — L2 exchange
    unsigned char* __restrict__ rsh,     // (256,1024) fp8 r*state — L2 exchange
    int* flags, int* claim, float* __restrict__ outacc)
{
    __shared__ __align__(16) char smem[98304];
    __shared__ int sh_gid[2];
    const int tid = threadIdx.x;
    if (tid == 0) {
        int xcd;
        asm volatile("s_getreg_b32 %0, hwreg(HW_REG_XCC_ID)" : "=s"(xcd));
        xcd &= 7;
        sh_gid[0] = xcd;
        sh_gid[1] = atomicAdd(&claim[xcd*64], 1) & 31;
    }
    __syncthreads();
    const int g = sh_gid[0], j = sh_gid[1];
    const int gbase = g*32, grow0 = g*32;
    const int w = tid >> 6, l = tid & 63;
    const int lh = l >> 4, ll = l & 15;
    const int mi = w >> 1, nc = w & 1;

    // ---- LDS: W12 state-part fp8 x8 (k-major) ----
    for (int u = tid; u < 64*128; u += 256) {
        int row = u >> 7, slot = u & 127;
        const float* src = (row < 32 ? W1 + (size_t)(32*j + row)*K1
                                     : W2 + (size_t)(32*j + row-32)*K1) + slot*8;
        unsigned lo = 0, hi = 0;
        lo = __builtin_amdgcn_cvt_pk_fp8_f32(src[0]*8.f, src[1]*8.f, lo, false);
        lo = __builtin_amdgcn_cvt_pk_fp8_f32(src[2]*8.f, src[3]*8.f, lo, true);
        hi = __builtin_amdgcn_cvt_pk_fp8_f32(src[4]*8.f, src[5]*8.f, hi, false);
        hi = __builtin_amdgcn_cvt_pk_fp8_f32(src[6]*8.f, src[7]*8.f, hi, true);
        uint2 o; o.x = lo; o.y = hi;
        *(uint2*)(smem + W12S_OFF + ((size_t)slot*64 + row)*8) = o;
    }
    // ---- W3 state-part fp8 x8 (k-major) ----
    for (int u = tid; u < 32*128; u += 256) {
        int row = u >> 7, slot = u & 127;
        const float* src = W3 + (size_t)(32*j + row)*K1 + slot*8;
        unsigned lo = 0, hi = 0;
        lo = __builtin_amdgcn_cvt_pk_fp8_f32(src[0]*8.f, src[1]*8.f, lo, false);
        lo = __builtin_amdgcn_cvt_pk_fp8_f32(src[2]*8.f, src[3]*8.f, lo, true);
        hi = __builtin_amdgcn_cvt_pk_fp8_f32(src[4]*8.f, src[5]*8.f, hi, false);
        hi = __builtin_amdgcn_cvt_pk_fp8_f32(src[6]*8.f, src[7]*8.f, hi, true);
        uint2 o; o.x = lo; o.y = hi;
        *(uint2*)(smem + W3S_OFF + ((size_t)slot*32 + row)*8) = o;
    }
    __syncthreads();

    const int colU = j*32 + nc*16 + ll;
    const float woc = Wo[colU];
    const int crow0 = grow0 + mi*16 + lh*4;

    const unsigned char* srow_s = ssh + ((size_t)(grow0 + mi*16 + ll) << 10) + lh*8;
    const unsigned char* srow_r = rsh + ((size_t)(grow0 + mi*16 + ll) << 10) + lh*8;

    float S_reg[4] = {0.f,0.f,0.f,0.f};
    float pout[4]  = {0.f,0.f,0.f,0.f};
    int it = 0;

    #define SEC1(S, AB) do { \
        _Pragma("unroll") for (int kf = 0; kf < 4; ++kf) { \
            const int kx = (S)*4 + kf; \
            long long a = __builtin_bit_cast(long long, AB[kx]); \
            long long bu = __builtin_bit_cast(long long, \
                *(const uint2*)(smem + W12S_OFF + (((kx*4+lh)*64) + nc*16 + ll)*8)); \
            long long br = __builtin_bit_cast(long long, \
                *(const uint2*)(smem + W12S_OFF + (((kx*4+lh)*64) + 32 + nc*16 + ll)*8)); \
            accu = __builtin_amdgcn_mfma_f32_16x16x32_fp8_fp8(a, bu, accu, 0,0,0); \
            accr = __builtin_amdgcn_mfma_f32_16x16x32_fp8_fp8(a, br, accr, 0,0,0); \
        } } while(0)
    #define SEC2(S, AB) do { \
        _Pragma("unroll") for (int kf = 0; kf < 4; ++kf) { \
            const int kx = (S)*4 + kf; \
            long long a = __builtin_bit_cast(long long, AB[kx]); \
            long long b = __builtin_bit_cast(long long, \
                *(const uint2*)(smem + W3S_OFF + (((kx*4+lh)*32) + nc*16 + ll)*8)); \
            acc2 = __builtin_amdgcn_mfma_f32_16x16x32_fp8_fp8(a, b, acc2, 0,0,0); \
        } } while(0)

    // ---- prologue prefetch: xcu/xcr for t=0 ----
    unsigned xcu[4], xcr[4];
    #pragma unroll
    for (int r = 0; r < 4; ++r)
        xcu[r] = ld_u16p(xc12 + ((size_t)(crow0 + r)*T_)*2048 + colU);
    #pragma unroll
    for (int r = 0; r < 4; ++r)
        xcr[r] = ld_u16p(xc12 + ((size_t)(crow0 + r)*T_)*2048 + 1024 + colU);
    waitv0_();

    for (int t = 0; t < T_; ++t) {
        const int tn = (t < T_-1) ? t+1 : t;
        float u_reg[4];
        unsigned xc3v[4], bv[4];
        { // ---- P1: u,r = sigmoid(0.125*(fp8 s @ fp8 8*W12s^T) + Xc12) ----
            uint2 ab1[32];
            #pragma unroll
            for (int k2 = 0; k2 < 32; ++k2)
                ab1[k2] = ld_l2_b64(srow_s + k2*32);
            #pragma unroll
            for (int r = 0; r < 4; ++r)
                xc3v[r] = ld_u16p(xc3 + ((size_t)(crow0 + r)*T_ + t)*1024 + colU);
            #pragma unroll
            for (int r = 0; r < 4; ++r)
                bv[r] = ld_u16p(belh + ((size_t)(crow0 + r)*T_ + tn)*H_ + colU);
            f32x4 accu = {}, accr = {};
            WAITV(36); SEC1(0, ab1);
            WAITV(32); SEC1(1, ab1);
            WAITV(28); SEC1(2, ab1);
            WAITV(24); SEC1(3, ab1);
            WAITV(20); SEC1(4, ab1);
            WAITV(16); SEC1(5, ab1);
            WAITV(12); SEC1(6, ab1);
            WAITV(8);  SEC1(7, ab1);
            #pragma unroll
            for (int r = 0; r < 4; ++r) {
                unsigned short uu16 = (unsigned short)xcu[r], rr16 = (unsigned short)xcr[r];
                float uu = sigmoidf_(accu[r]*0.125f + (float)(*(_Float16*)&uu16));
                float rr = sigmoidf_(accr[r]*0.125f + (float)(*(_Float16*)&rr16));
                u_reg[r] = uu;
                st_l2_u8(rsh + ((size_t)(crow0 + r) << 10) + colU, to_fp8(rr * S_reg[r]));
            }
        }
        group_barrier32(flags, gbase, j, ++it, w, l);
        { // ---- P2: ns = tanh(0.125*(fp8 r*s @ fp8 8*W3s^T) + Xc3); update ----
            uint2 ab2[32];
            #pragma unroll
            for (int k2 = 0; k2 < 32; ++k2)
                ab2[k2] = ld_l2_b64(srow_r + k2*32);
            #pragma unroll
            for (int r = 0; r < 4; ++r)
                xcu[r] = ld_u16p(xc12 + ((size_t)(crow0 + r)*T_ + tn)*2048 + colU);
            #pragma unroll
            for (int r = 0; r < 4; ++r)
                xcr[r] = ld_u16p(xc12 + ((size_t)(crow0 + r)*T_ + tn)*2048 + 1024 + colU);
            f32x4 acc2 = {};
            WAITV(36); SEC2(0, ab2);
            WAITV(32); SEC2(1, ab2);
            WAITV(28); SEC2(2, ab2);
            WAITV(24); SEC2(3, ab2);
            WAITV(20); SEC2(4, ab2);
            WAITV(16); SEC2(5, ab2);
            WAITV(12); SEC2(6, ab2);
            WAITV(8);  SEC2(7, ab2);
            #pragma unroll
            for (int r = 0; r < 4; ++r) {
                unsigned short x16 = (unsigned short)xc3v[r];
                float ns = tanhf_(acc2[r]*0.125f + (float)(*(_Float16*)&x16));
                float sn = (1.f - u_reg[r])*S_reg[r] + u_reg[r]*ns;
                if (t < T_-1) {
                    unsigned short us = (unsigned short)bv[r];
                    float bel = (float)(*(_Float16*)&us);
                    float ss = bel * sn;
                    S_reg[r] = ss;
                    st_l2_u8(ssh + ((size_t)(crow0 + r) << 10) + colU, to_fp8(ss));
                } else {
                    pout[r] = sn * woc;
                }
            }
        }
        group_barrier32(flags, gbase, j, ++it, w, l);
    }
    #undef SEC1
    #undef SEC2
    // ---- final: sum pout over this wave's 16 cols, atomicAdd per row ----
    #pragma unroll
    for (int r = 0; r < 4; ++r) {
        float v = pout[r];
        v += __shfl_xor(v, 1, 64);
        v += __shfl_xor(v, 2, 64);
        v += __shfl_xor(v, 4, 64);
        v += __shfl_xor(v, 8, 64);
        if (ll == 0) atomicAdd(&outacc[crow0 + r], v);
    }
}

__global__ void finish_k(const float* __restrict__ acc, const float* __restrict__ bo,
                         float* __restrict__ out) {
    int i = threadIdx.x;
    out[i] = sigmoidf_(acc[i] + bo[0]);
}

extern "C" void kernel_launch(void* const* d_in, const int* in_sizes, int n_in,
                              void* d_out, int out_size, void* d_ws, size_t ws_size,
                              hipStream_t stream) {
    const float* x   = (const float*)d_in[0];
    const float* td  = (const float*)d_in[1];
    const float* Wb  = (const float*)d_in[2];
    const float* bb  = (const float*)d_in[3];
    const float* W1  = (const float*)d_in[4];
    const float* b1  = (const float*)d_in[5];
    const float* W2  = (const float*)d_in[6];
    const float* b2  = (const float*)d_in[7];
    const float* W3  = (const float*)d_in[8];
    const float* b3  = (const float*)d_in[9];
    const float* Wo  = (const float*)d_in[10];
    const float* bo  = (const float*)d_in[11];
    float* out = (float*)d_out;

    char* p = (char*)d_ws;
    auto carve = [&](size_t bytes) { char* r = p; p += (bytes + 255) & ~(size_t)255; return r; };
    int*           bar    = (int*)           carve(32768);             // 256 flag-lines
    int*           claim  = (int*)           carve(2048);              // 8 XCD counters, padded
    float*         outacc = (float*)         carve(1024);
    unsigned char* ssh    = (unsigned char*) carve((size_t)B_*H_);     // fp8 state
    unsigned char* rsh    = (unsigned char*) carve((size_t)B_*H_);     // fp8 r*state
    _Float16*      xh     = (_Float16*)      carve((size_t)NT*IN_*2);
    _Float16*      tdh    = (_Float16*)      carve((size_t)NT*IN_*2);
    _Float16*      belh   = (_Float16*)      carve((size_t)NT*H_*2);
    _Float16*      Wbh    = (_Float16*)      carve((size_t)H_*IN_*2);
    _Float16*      wx12h  = (_Float16*)      carve((size_t)2048*512*2);
    _Float16*      wx3h   = (_Float16*)      carve((size_t)1024*512*2);
    _Float16*      xc12   = (_Float16*)      carve((size_t)NT*2048*2);
    _Float16*      xc3    = (_Float16*)      carve((size_t)NT*1024*2);

    size_t zbytes = 32768 + 2048 + 1024 + (size_t)B_*H_;
    (void)hipMemsetAsync(bar, 0, zbytes, stream);

    prep_cvt_k<<<2048, 256, 0, stream>>>(x, td, Wb, W1, W2, W3,
                                         xh, tdh, Wbh, wx12h, wx3h);

    belta_gemm_k<<<(NT/64)*(H_/128), 256, 0, stream>>>(tdh, Wbh, bb, belh);
    xc_gemm_k<<<(NT/64)*(2048/128), 256, 0, stream>>>(xh, wx12h, b1, b2, xc12, 2048, 16);
    xc_gemm_k<<<(NT/64)*(1024/128), 256, 0, stream>>>(xh, wx3h,  b3, b3, xc3,  1024, 8);

    recur_k<<<256, 256, 0, stream>>>(belh, W1, W2, W3, xc12, xc3, Wo,
                                     ssh, rsh, bar, claim, outacc);
    finish_k<<<1, 256, 0, stream>>>(outacc, bo, out);
}